// Round 1
// baseline (941.032 us; speedup 1.0000x reference)
//
#include <hip/hip_runtime.h>

#define NU 100000
#define NI 100000
#define NEDGE 600000
#define DIN 128
#define DOUT 16
#define TR 64

// ---------------- CSR build ----------------
__global__ void hist_kernel(const int* __restrict__ dst, int* __restrict__ off, int nE) {
  int e = blockIdx.x * blockDim.x + threadIdx.x;
  if (e < nE) atomicAdd(&off[dst[e] + 1], 1);
}

// one block per etype; inclusive scan over n=NU+1 ints in place
__global__ void scan3_kernel(int* off_uu, int* off_iu, int* off_ui, int n) {
  int* off = (blockIdx.x == 0) ? off_uu : (blockIdx.x == 1) ? off_iu : off_ui;
  __shared__ int wsum[16];
  int tid = threadIdx.x;
  int lane = tid & 63, wv = tid >> 6;
  int carry = 0;
  for (int base = 0; base < n; base += 1024) {
    int i = base + tid;
    int x = (i < n) ? off[i] : 0;
#pragma unroll
    for (int d = 1; d < 64; d <<= 1) {
      int y = __shfl_up(x, d, 64);
      if (lane >= d) x += y;
    }
    if (lane == 63) wsum[wv] = x;
    __syncthreads();
    if (wv == 0 && lane < 16) {
      int t = wsum[lane];
#pragma unroll
      for (int d = 1; d < 16; d <<= 1) {
        int y = __shfl_up(t, d, 16);
        if ((lane & 15) >= d) t += y;
      }
      wsum[lane] = t;
    }
    __syncthreads();
    int add = carry + (wv > 0 ? wsum[wv - 1] : 0);
    if (i < n) off[i] = x + add;
    carry += wsum[15];
    __syncthreads();
  }
}

__global__ void curinit_kernel(int* __restrict__ cur, const int* __restrict__ off_uu,
                               const int* __restrict__ off_iu, const int* __restrict__ off_ui) {
  int i = blockIdx.x * blockDim.x + threadIdx.x;
  if (i < NU) cur[i] = off_uu[i];
  else if (i < 2 * NU) cur[i] = off_iu[i - NU];
  else if (i < 3 * NU) cur[i] = off_ui[i - 2 * NU];
}

__global__ void scatter_kernel(const int* __restrict__ src, const int* __restrict__ dst,
                               int* __restrict__ cur, int* __restrict__ ssrc, int nE) {
  int e = blockIdx.x * blockDim.x + threadIdx.x;
  if (e < nE) {
    int pos = atomicAdd(&cur[dst[e]], 1);
    ssrc[pos] = src[e];
  }
}

// ---------------- segment mean, 128-dim: one wave per dst node ----------------
__global__ __launch_bounds__(256) void agg_mean128(const float* __restrict__ X,
                                                   const int* __restrict__ off,
                                                   const int* __restrict__ ssrc,
                                                   float* __restrict__ out, int n) {
  int node = blockIdx.x * 4 + (threadIdx.x >> 6);
  int lane = threadIdx.x & 63;
  if (node >= n) return;
  int s0 = off[node], s1 = off[node + 1];
  float ax = 0.f, ay = 0.f;
  for (int e = s0; e < s1; e++) {
    int s = ssrc[e];
    const float2* xr = (const float2*)(X + (size_t)s * DIN);
    float2 v = xr[lane];
    ax += v.x; ay += v.y;
  }
  float inv = 1.0f / fmaxf((float)(s1 - s0), 1.0f);
  float2 r; r.x = ax * inv; r.y = ay * inv;
  ((float2*)(out + (size_t)node * DIN))[lane] = r;
}

// ---------------- fused rows: h = relu(A0@W0a + b0a*m0 + A1@W0b + b0b*m1); P = h@W1 + b1 ----------------
__global__ __launch_bounds__(256) void user_rows_kernel(
    const float* __restrict__ A0, const int* __restrict__ off0,
    const float* __restrict__ W0a, const float* __restrict__ b0a,
    const float* __restrict__ A1, const int* __restrict__ off1,
    const float* __restrict__ W0b, const float* __restrict__ b0b,
    const float* __restrict__ W1, const float* __restrict__ b1,
    float* __restrict__ P, int nrows) {
  __shared__ float a0s[TR][36];
  __shared__ float a1s[TR][36];
  __shared__ float hs[TR][132];

  const int tid = threadIdx.x;
  const int row0 = blockIdx.x * TR;
  const int rg = tid >> 4;
  const int c0 = (tid & 15) << 3;

  float ba[8], bb[8];
  *(float4*)&ba[0] = *(const float4*)&b0a[c0];
  *(float4*)&ba[4] = *(const float4*)&b0a[c0 + 4];
  *(float4*)&bb[0] = *(const float4*)&b0b[c0];
  *(float4*)&bb[4] = *(const float4*)&b0b[c0 + 4];

  float acc[4][8];
#pragma unroll
  for (int i = 0; i < 4; i++) {
    int row = row0 + rg * 4 + i;
    float m0 = 0.f, m1 = 0.f;
    if (row < nrows) {
      m0 = (off0[row + 1] > off0[row]) ? 1.f : 0.f;
      m1 = (off1[row + 1] > off1[row]) ? 1.f : 0.f;
    }
#pragma unroll
    for (int j = 0; j < 8; j++) acc[i][j] = ba[j] * m0 + bb[j] * m1;
  }

  for (int kc = 0; kc < DIN; kc += 32) {
    __syncthreads();
#pragma unroll
    for (int s = 0; s < 2; s++) {
      int fid = tid * 2 + s;
      int rl = fid >> 3, q = fid & 7;
      int row = row0 + rl;
      float4 v0 = make_float4(0.f, 0.f, 0.f, 0.f);
      float4 v1 = v0;
      if (row < nrows) {
        v0 = *(const float4*)&A0[(size_t)row * DIN + kc + q * 4];
        v1 = *(const float4*)&A1[(size_t)row * DIN + kc + q * 4];
      }
      *(float4*)&a0s[rl][q * 4] = v0;
      *(float4*)&a1s[rl][q * 4] = v1;
    }
    __syncthreads();
#pragma unroll 4
    for (int kk = 0; kk < 32; kk++) {
      int k = kc + kk;
      float4 wa0 = *(const float4*)&W0a[k * DIN + c0];
      float4 wa1 = *(const float4*)&W0a[k * DIN + c0 + 4];
      float4 wb0 = *(const float4*)&W0b[k * DIN + c0];
      float4 wb1 = *(const float4*)&W0b[k * DIN + c0 + 4];
#pragma unroll
      for (int i = 0; i < 4; i++) {
        float av = a0s[rg * 4 + i][kk];
        float bv = a1s[rg * 4 + i][kk];
        acc[i][0] += av * wa0.x; acc[i][0] += bv * wb0.x;
        acc[i][1] += av * wa0.y; acc[i][1] += bv * wb0.y;
        acc[i][2] += av * wa0.z; acc[i][2] += bv * wb0.z;
        acc[i][3] += av * wa0.w; acc[i][3] += bv * wb0.w;
        acc[i][4] += av * wa1.x; acc[i][4] += bv * wb1.x;
        acc[i][5] += av * wa1.y; acc[i][5] += bv * wb1.y;
        acc[i][6] += av * wa1.z; acc[i][6] += bv * wb1.z;
        acc[i][7] += av * wa1.w; acc[i][7] += bv * wb1.w;
      }
    }
  }

#pragma unroll
  for (int i = 0; i < 4; i++) {
    int r = rg * 4 + i;
    float4 h0, h1;
    h0.x = fmaxf(acc[i][0], 0.f); h0.y = fmaxf(acc[i][1], 0.f);
    h0.z = fmaxf(acc[i][2], 0.f); h0.w = fmaxf(acc[i][3], 0.f);
    h1.x = fmaxf(acc[i][4], 0.f); h1.y = fmaxf(acc[i][5], 0.f);
    h1.z = fmaxf(acc[i][6], 0.f); h1.w = fmaxf(acc[i][7], 0.f);
    *(float4*)&hs[r][c0] = h0;
    *(float4*)&hs[r][c0 + 4] = h1;
  }
  __syncthreads();

  const int il = tid >> 2;
  const int o0 = (tid & 3) << 2;
  float4 acc2 = *(const float4*)&b1[o0];
#pragma unroll 8
  for (int k = 0; k < DIN; k++) {
    float hv = hs[il][k];
    float4 w = *(const float4*)&W1[k * DOUT + o0];
    acc2.x += hv * w.x; acc2.y += hv * w.y;
    acc2.z += hv * w.z; acc2.w += hv * w.w;
  }
  int row = row0 + il;
  if (row < nrows) *(float4*)&P[(size_t)row * DOUT + o0] = acc2;
}

__global__ __launch_bounds__(256) void item_rows_kernel(
    const float* __restrict__ A0, const int* __restrict__ off0,
    const float* __restrict__ W0a, const float* __restrict__ b0a,
    const float* __restrict__ W1, const float* __restrict__ b1,
    float* __restrict__ P, int nrows) {
  __shared__ float a0s[TR][36];
  __shared__ float hs[TR][132];

  const int tid = threadIdx.x;
  const int row0 = blockIdx.x * TR;
  const int rg = tid >> 4;
  const int c0 = (tid & 15) << 3;

  float ba[8];
  *(float4*)&ba[0] = *(const float4*)&b0a[c0];
  *(float4*)&ba[4] = *(const float4*)&b0a[c0 + 4];

  float acc[4][8];
#pragma unroll
  for (int i = 0; i < 4; i++) {
    int row = row0 + rg * 4 + i;
    float m0 = 0.f;
    if (row < nrows) m0 = (off0[row + 1] > off0[row]) ? 1.f : 0.f;
#pragma unroll
    for (int j = 0; j < 8; j++) acc[i][j] = ba[j] * m0;
  }

  for (int kc = 0; kc < DIN; kc += 32) {
    __syncthreads();
#pragma unroll
    for (int s = 0; s < 2; s++) {
      int fid = tid * 2 + s;
      int rl = fid >> 3, q = fid & 7;
      int row = row0 + rl;
      float4 v0 = make_float4(0.f, 0.f, 0.f, 0.f);
      if (row < nrows) v0 = *(const float4*)&A0[(size_t)row * DIN + kc + q * 4];
      *(float4*)&a0s[rl][q * 4] = v0;
    }
    __syncthreads();
#pragma unroll 4
    for (int kk = 0; kk < 32; kk++) {
      int k = kc + kk;
      float4 wa0 = *(const float4*)&W0a[k * DIN + c0];
      float4 wa1 = *(const float4*)&W0a[k * DIN + c0 + 4];
#pragma unroll
      for (int i = 0; i < 4; i++) {
        float av = a0s[rg * 4 + i][kk];
        acc[i][0] += av * wa0.x; acc[i][1] += av * wa0.y;
        acc[i][2] += av * wa0.z; acc[i][3] += av * wa0.w;
        acc[i][4] += av * wa1.x; acc[i][5] += av * wa1.y;
        acc[i][6] += av * wa1.z; acc[i][7] += av * wa1.w;
      }
    }
  }

#pragma unroll
  for (int i = 0; i < 4; i++) {
    int r = rg * 4 + i;
    float4 h0, h1;
    h0.x = fmaxf(acc[i][0], 0.f); h0.y = fmaxf(acc[i][1], 0.f);
    h0.z = fmaxf(acc[i][2], 0.f); h0.w = fmaxf(acc[i][3], 0.f);
    h1.x = fmaxf(acc[i][4], 0.f); h1.y = fmaxf(acc[i][5], 0.f);
    h1.z = fmaxf(acc[i][6], 0.f); h1.w = fmaxf(acc[i][7], 0.f);
    *(float4*)&hs[r][c0] = h0;
    *(float4*)&hs[r][c0 + 4] = h1;
  }
  __syncthreads();

  const int il = tid >> 2;
  const int o0 = (tid & 3) << 2;
  float4 acc2 = *(const float4*)&b1[o0];
#pragma unroll 8
  for (int k = 0; k < DIN; k++) {
    float hv = hs[il][k];
    float4 w = *(const float4*)&W1[k * DOUT + o0];
    acc2.x += hv * w.x; acc2.y += hv * w.y;
    acc2.z += hv * w.z; acc2.w += hv * w.w;
  }
  int row = row0 + il;
  if (row < nrows) *(float4*)&P[(size_t)row * DOUT + o0] = acc2;
}

// ---------------- layer-1 segment mean over 16-dim P ----------------
__global__ __launch_bounds__(256) void out_agg16(const float* __restrict__ P,
                                                 const int* __restrict__ off,
                                                 const int* __restrict__ ssrc,
                                                 float* __restrict__ out, int n, int accumulate) {
  int node = blockIdx.x * 4 + (threadIdx.x >> 6);
  int lane = threadIdx.x & 63;
  if (node >= n) return;
  int s0 = off[node], s1 = off[node + 1];
  int sub = lane >> 4;
  int elem = lane & 15;
  float acc = 0.f;
  for (int e = s0 + sub; e < s1; e += 4) {
    int s = ssrc[e];
    acc += P[(size_t)s * DOUT + elem];
  }
  acc += __shfl_xor(acc, 16, 64);
  acc += __shfl_xor(acc, 32, 64);
  float inv = 1.0f / fmaxf((float)(s1 - s0), 1.0f);
  if (lane < 16) {
    float v = acc * inv;
    if (accumulate) out[(size_t)node * DOUT + elem] += v;
    else out[(size_t)node * DOUT + elem] = v;
  }
}

extern "C" void kernel_launch(void* const* d_in, const int* in_sizes, int n_in,
                              void* d_out, int out_size, void* d_ws, size_t ws_size,
                              hipStream_t stream) {
  const float* embed_user = (const float*)d_in[0];
  const float* embed_item = (const float*)d_in[1];
  const int* src_uu = (const int*)d_in[2];
  const int* dst_uu = (const int*)d_in[3];
  const int* src_ui = (const int*)d_in[4];
  const int* dst_ui = (const int*)d_in[5];
  const int* src_iu = (const int*)d_in[6];
  const int* dst_iu = (const int*)d_in[7];
  const float* W0_uu = (const float*)d_in[8];
  const float* b0_uu = (const float*)d_in[9];
  const float* W0_ui = (const float*)d_in[10];
  const float* b0_ui = (const float*)d_in[11];
  const float* W0_iu = (const float*)d_in[12];
  const float* b0_iu = (const float*)d_in[13];
  const float* W1_uu = (const float*)d_in[14];
  const float* b1_uu = (const float*)d_in[15];
  const float* W1_iu = (const float*)d_in[18];
  const float* b1_iu = (const float*)d_in[19];
  float* out = (float*)d_out;

  float* wsf = (float*)d_ws;
  int* wsi = (int*)d_ws;
  // workspace layout (4-byte words); peak use ~118.4 MB
  float* buf0 = wsf;                    // 12,800,000 f  (A_ui mean, then A_uu mean)
  float* buf1 = wsf + 12800000;         // 12,800,000 f  (A_iu feature mean)
  float* P = wsf + 25600000;            // 1,600,000 f   (P_iu then P_uu)
  int* off_uu = wsi + 27200000;         // 100,001 ints each (slotted 100,016)
  int* off_iu = wsi + 27300016;
  int* off_ui = wsi + 27400032;
  int* cur = wsi + 27500048;            // 3 * 100,000 ints
  int* ssrc_uu = wsi + 27800048;        // 600,000 ints each
  int* ssrc_iu = wsi + 28400048;
  int* ssrc_ui = wsi + 29000048;

  // zero histogram/offset regions (single contiguous span covering all 3 slots)
  hipMemsetAsync(off_uu, 0, (size_t)(27500048 - 27200000) * sizeof(int), stream);

  const int eb = (NEDGE + 255) / 256;
  hist_kernel<<<eb, 256, 0, stream>>>(dst_uu, off_uu, NEDGE);
  hist_kernel<<<eb, 256, 0, stream>>>(dst_iu, off_iu, NEDGE);
  hist_kernel<<<eb, 256, 0, stream>>>(dst_ui, off_ui, NEDGE);
  scan3_kernel<<<3, 1024, 0, stream>>>(off_uu, off_iu, off_ui, NU + 1);
  curinit_kernel<<<(3 * NU + 255) / 256, 256, 0, stream>>>(cur, off_uu, off_iu, off_ui);
  scatter_kernel<<<eb, 256, 0, stream>>>(src_uu, dst_uu, cur, ssrc_uu, NEDGE);
  scatter_kernel<<<eb, 256, 0, stream>>>(src_iu, dst_iu, cur + NU, ssrc_iu, NEDGE);
  scatter_kernel<<<eb, 256, 0, stream>>>(src_ui, dst_ui, cur + 2 * NU, ssrc_ui, NEDGE);

  const int nb4 = (NU + 3) / 4;
  const int nbr = (NU + TR - 1) / TR;

  // ---- item path: A_ui -> P_iu -> out (write) ----
  agg_mean128<<<nb4, 256, 0, stream>>>(embed_user, off_ui, ssrc_ui, buf0, NI);
  item_rows_kernel<<<nbr, 256, 0, stream>>>(buf0, off_ui, W0_ui, b0_ui, W1_iu, b1_iu, P, NI);
  out_agg16<<<nb4, 256, 0, stream>>>(P, off_iu, ssrc_iu, out, NU, 0);

  // ---- user path: A_uu, A_iu -> P_uu -> out (accumulate) ----
  agg_mean128<<<nb4, 256, 0, stream>>>(embed_user, off_uu, ssrc_uu, buf0, NU);
  agg_mean128<<<nb4, 256, 0, stream>>>(embed_item, off_iu, ssrc_iu, buf1, NU);
  user_rows_kernel<<<nbr, 256, 0, stream>>>(buf0, off_uu, W0_uu, b0_uu,
                                            buf1, off_iu, W0_iu, b0_iu,
                                            W1_uu, b1_uu, P, NU);
  out_agg16<<<nb4, 256, 0, stream>>>(P, off_uu, ssrc_uu, out, NU, 1);
}

// Round 2
// 697.164 us; speedup vs baseline: 1.3498x; 1.3498x over previous
//
#include <hip/hip_runtime.h>
#include <hip/hip_bf16.h>

#define NU 100000
#define NI 100000
#define NEDGE 600000
#define DIN 128
#define DOUT 16
#define NPAD 100032   // 1563 * 64

typedef __attribute__((ext_vector_type(8))) short short8;
typedef __attribute__((ext_vector_type(4))) float f32x4;

__device__ inline unsigned pack_bf16(float x, float y) {
  __hip_bfloat162 h = __float22bfloat162_rn(make_float2(x, y));
  unsigned u;
  __builtin_memcpy(&u, &h, 4);
  return u;
}

__device__ inline short bf16_bits(float x) {
  __hip_bfloat16 h = __float2bfloat16(x);
  short s;
  __builtin_memcpy(&s, &h, 2);
  return s;
}

// ---------------- CSR build ----------------
__global__ void hist3_kernel(const int* __restrict__ d_uu, const int* __restrict__ d_iu,
                             const int* __restrict__ d_ui, int* __restrict__ off_uu,
                             int* __restrict__ off_iu, int* __restrict__ off_ui, int eb) {
  int seg = blockIdx.x / eb;
  int e = (blockIdx.x % eb) * 256 + threadIdx.x;
  if (e >= NEDGE) return;
  const int* d = (seg == 0) ? d_uu : (seg == 1) ? d_iu : d_ui;
  int* off = (seg == 0) ? off_uu : (seg == 1) ? off_iu : off_ui;
  atomicAdd(&off[d[e] + 1], 1);
}

// one block per etype; inclusive scan over n ints in place
__global__ void scan3_kernel(int* off_uu, int* off_iu, int* off_ui, int n) {
  int* off = (blockIdx.x == 0) ? off_uu : (blockIdx.x == 1) ? off_iu : off_ui;
  __shared__ int wsum[16];
  int tid = threadIdx.x;
  int lane = tid & 63, wv = tid >> 6;
  int carry = 0;
  for (int base = 0; base < n; base += 1024) {
    int i = base + tid;
    int x = (i < n) ? off[i] : 0;
#pragma unroll
    for (int d = 1; d < 64; d <<= 1) {
      int y = __shfl_up(x, d, 64);
      if (lane >= d) x += y;
    }
    if (lane == 63) wsum[wv] = x;
    __syncthreads();
    if (wv == 0 && lane < 16) {
      int t = wsum[lane];
#pragma unroll
      for (int d = 1; d < 16; d <<= 1) {
        int y = __shfl_up(t, d, 16);
        if ((lane & 15) >= d) t += y;
      }
      wsum[lane] = t;
    }
    __syncthreads();
    int add = carry + (wv > 0 ? wsum[wv - 1] : 0);
    if (i < n) off[i] = x + add;
    carry += wsum[15];
    __syncthreads();
  }
}

__global__ void curinit_kernel(int* __restrict__ cur, const int* __restrict__ off_uu,
                               const int* __restrict__ off_iu, const int* __restrict__ off_ui) {
  int i = blockIdx.x * blockDim.x + threadIdx.x;
  if (i < NU) cur[i] = off_uu[i];
  else if (i < 2 * NU) cur[i] = off_iu[i - NU];
  else if (i < 3 * NU) cur[i] = off_ui[i - 2 * NU];
}

__global__ void scatter3_kernel(const int* __restrict__ s_uu, const int* __restrict__ d_uu,
                                const int* __restrict__ s_iu, const int* __restrict__ d_iu,
                                const int* __restrict__ s_ui, const int* __restrict__ d_ui,
                                int* __restrict__ cur, int* __restrict__ ssrc_uu,
                                int* __restrict__ ssrc_iu, int* __restrict__ ssrc_ui, int eb) {
  int seg = blockIdx.x / eb;
  int e = (blockIdx.x % eb) * 256 + threadIdx.x;
  if (e >= NEDGE) return;
  const int* src = (seg == 0) ? s_uu : (seg == 1) ? s_iu : s_ui;
  const int* dst = (seg == 0) ? d_uu : (seg == 1) ? d_iu : d_ui;
  int* curp = cur + seg * NU;
  int* out = (seg == 0) ? ssrc_uu : (seg == 1) ? ssrc_iu : ssrc_ui;
  int pos = atomicAdd(&curp[dst[e]], 1);
  out[pos] = src[e];
}

// ---------------- weight repack into MFMA B-fragment order (bf16) ----------------
// W0 pack: p[(kc*8+nt)*512 + lane*8 + j] = W0[(kc*32 + (lane>>4)*8 + j)*128 + nt*16 + (lane&15)]
// W1 pack: p[kc*512 + lane*8 + j]        = W1[(kc*32 + (lane>>4)*8 + j)*16  + (lane&15)]
__global__ void repack_kernel(const float* __restrict__ W0_uu, const float* __restrict__ W0_ui,
                              const float* __restrict__ W0_iu, const float* __restrict__ W1_uu,
                              const float* __restrict__ W1_iu, short* __restrict__ pW0_uu,
                              short* __restrict__ pW0_ui, short* __restrict__ pW0_iu,
                              short* __restrict__ pW1_uu, short* __restrict__ pW1_iu) {
  int t = blockIdx.x * 256 + threadIdx.x;
  const float* src;
  short* dst;
  int base;
  bool w1 = false;
  if (t < 16384) { src = W0_uu; dst = pW0_uu; base = t; }
  else if (t < 32768) { src = W0_ui; dst = pW0_ui; base = t - 16384; }
  else if (t < 49152) { src = W0_iu; dst = pW0_iu; base = t - 32768; }
  else if (t < 51200) { src = W1_uu; dst = pW1_uu; base = t - 49152; w1 = true; }
  else if (t < 53248) { src = W1_iu; dst = pW1_iu; base = t - 51200; w1 = true; }
  else return;
  int j = base & 7;
  int lane = (base >> 3) & 63;
  int frag = base >> 9;
  int quad = lane >> 4, l16 = lane & 15;
  float val;
  if (!w1) {
    int kc = frag >> 3, nt = frag & 7;
    val = src[(kc * 32 + quad * 8 + j) * 128 + nt * 16 + l16];
  } else {
    int kc = frag;
    val = src[(kc * 32 + quad * 8 + j) * 16 + l16];
  }
  dst[base] = bf16_bits(val);
}

// ---------------- segment mean (3 etypes, one dispatch): fp32 gather -> bf16 rows ----------------
__global__ __launch_bounds__(256) void agg3_kernel(
    const float* __restrict__ Xu, const float* __restrict__ Xi,
    const int* __restrict__ off_ui, const int* __restrict__ off_uu, const int* __restrict__ off_iu,
    const int* __restrict__ s_ui, const int* __restrict__ s_uu, const int* __restrict__ s_iu,
    __hip_bfloat162* __restrict__ A_ui, __hip_bfloat162* __restrict__ A_uu,
    __hip_bfloat162* __restrict__ A_iu, int nb1) {
  int seg = blockIdx.x / nb1;
  int node = (blockIdx.x % nb1) * 4 + (threadIdx.x >> 6);
  int lane = threadIdx.x & 63;
  const float* X;
  const int* off;
  const int* ss;
  __hip_bfloat162* A;
  if (seg == 0) { X = Xu; off = off_ui; ss = s_ui; A = A_ui; }
  else if (seg == 1) { X = Xu; off = off_uu; ss = s_uu; A = A_uu; }
  else { X = Xi; off = off_iu; ss = s_iu; A = A_iu; }
  if (node >= NPAD) return;
  float ax = 0.f, ay = 0.f;
  int deg = 0;
  if (node < NU) {
    int s0 = off[node], s1 = off[node + 1];
    deg = s1 - s0;
    int e = s0;
    // 4-way unrolled independent gathers for memory-level parallelism
    for (; e + 4 <= s1; e += 4) {
      int sa = ss[e], sb = ss[e + 1], sc = ss[e + 2], sd = ss[e + 3];
      float2 va = *(const float2*)(X + (size_t)sa * DIN + lane * 2);
      float2 vb = *(const float2*)(X + (size_t)sb * DIN + lane * 2);
      float2 vc = *(const float2*)(X + (size_t)sc * DIN + lane * 2);
      float2 vd = *(const float2*)(X + (size_t)sd * DIN + lane * 2);
      ax += (va.x + vb.x) + (vc.x + vd.x);
      ay += (va.y + vb.y) + (vc.y + vd.y);
    }
    for (; e < s1; e++) {
      int s = ss[e];
      float2 v = *(const float2*)(X + (size_t)s * DIN + lane * 2);
      ax += v.x;
      ay += v.y;
    }
  }
  float inv = 1.0f / fmaxf((float)deg, 1.0f);
  A[(size_t)node * 64 + lane] = __float22bfloat162_rn(make_float2(ax * inv, ay * inv));
}

// ---------------- fused MFMA rows: h = relu(A@W0 [+A1@W0b] + bias*mask); P = h@W1 + b1 ----------------
// blocks [0,nbi): item path; [nbi,2*nbi): user path. 64 rows/block, 16 rows/wave.
__global__ __launch_bounds__(256) void rows_mfma_kernel(
    const __hip_bfloat16* __restrict__ A_ui, const __hip_bfloat16* __restrict__ A_uu,
    const __hip_bfloat16* __restrict__ A_iu, const int* __restrict__ off_ui,
    const int* __restrict__ off_uu, const int* __restrict__ off_iu,
    const short* __restrict__ pW0_ui, const short* __restrict__ pW0_uu,
    const short* __restrict__ pW0_iu, const float* __restrict__ b0_ui,
    const float* __restrict__ b0_uu, const float* __restrict__ b0_iu,
    const short* __restrict__ pW1_iu, const short* __restrict__ pW1_uu,
    const float* __restrict__ b1_iu, const float* __restrict__ b1_uu,
    float* __restrict__ P_iu, float* __restrict__ P_uu, int nbi) {
  __shared__ float hs[4][2560];  // per-wave h staging: [col][row] fp32, row-pad 20

  const int tid = threadIdx.x;
  const int w = tid >> 6, lane = tid & 63;
  const int quad = lane >> 4, l16 = lane & 15;
  const bool user = (int)blockIdx.x >= nbi;
  const int blk = user ? (int)blockIdx.x - nbi : (int)blockIdx.x;
  const int rb = blk * 64 + w * 16;  // this wave's row base

  const __hip_bfloat16* A0 = user ? A_uu : A_ui;
  const int* off0 = user ? off_uu : off_ui;
  const short* W0a = user ? pW0_uu : pW0_ui;
  const float* b0a = user ? b0_uu : b0_ui;
  const short* W1p = user ? pW1_uu : pW1_iu;
  const float* b1v = user ? b1_uu : b1_iu;
  float* P = user ? P_uu : P_iu;

  // bias masks for this lane's 4 C-rows (row = quad*4 + reg)
  float m0[4], m1[4];
#pragma unroll
  for (int r = 0; r < 4; r++) {
    int rr = rb + quad * 4 + r;
    m0[r] = 0.f;
    m1[r] = 0.f;
    if (rr < NU) {
      m0[r] = (off0[rr + 1] > off0[rr]) ? 1.f : 0.f;
      if (user) m1[r] = (off_iu[rr + 1] > off_iu[rr]) ? 1.f : 0.f;
    }
  }

  f32x4 acc[8];
#pragma unroll
  for (int nt = 0; nt < 8; nt++) {
    float ba = b0a[nt * 16 + l16];
    float bb = user ? b0_iu[nt * 16 + l16] : 0.f;
#pragma unroll
    for (int r = 0; r < 4; r++) acc[nt][r] = ba * m0[r] + bb * m1[r];
  }

  // A fragments loaded directly from global (row-major bf16, 16B/lane contiguous)
  const short8* A0v = (const short8*)(A0 + (size_t)(rb + l16) * DIN);
  const short8* A1v = (const short8*)(A_iu + (size_t)(rb + l16) * DIN);
  const short8* B0p = (const short8*)W0a;
  const short8* B1p = (const short8*)pW0_iu;

#pragma unroll
  for (int kc = 0; kc < 4; kc++) {
    short8 a0 = A0v[kc * 4 + quad];
    short8 a1 = user ? A1v[kc * 4 + quad] : a0;
#pragma unroll
    for (int nt = 0; nt < 8; nt++) {
      short8 b0 = B0p[(kc * 8 + nt) * 64 + lane];
      acc[nt] = __builtin_amdgcn_mfma_f32_16x16x32_bf16(a0, b0, acc[nt], 0, 0, 0);
      if (user) {
        short8 bb = B1p[(kc * 8 + nt) * 64 + lane];
        acc[nt] = __builtin_amdgcn_mfma_f32_16x16x32_bf16(a1, bb, acc[nt], 0, 0, 0);
      }
    }
  }

  // relu + stage h to per-wave LDS [col][row(pad 20)]
  float* hw = &hs[w][0];
#pragma unroll
  for (int nt = 0; nt < 8; nt++) {
    int col = nt * 16 + l16;
    float4 v;
    v.x = fmaxf(acc[nt][0], 0.f);
    v.y = fmaxf(acc[nt][1], 0.f);
    v.z = fmaxf(acc[nt][2], 0.f);
    v.w = fmaxf(acc[nt][3], 0.f);
    *(float4*)&hw[col * 20 + quad * 4] = v;
  }
  __syncthreads();

  // second MFMA chain: P[16x16] = h[16x128] @ W1[128x16] + b1
  f32x4 acc2;
  {
    float bv = b1v[l16];
    acc2[0] = bv; acc2[1] = bv; acc2[2] = bv; acc2[3] = bv;
  }
  const short8* W1f = (const short8*)W1p;
#pragma unroll
  for (int kc = 0; kc < 4; kc++) {
    float f[8];
#pragma unroll
    for (int j = 0; j < 8; j++) f[j] = hw[(kc * 32 + quad * 8 + j) * 20 + l16];
    union { uint4 u; short8 s; } hf;
    hf.u.x = pack_bf16(f[0], f[1]);
    hf.u.y = pack_bf16(f[2], f[3]);
    hf.u.z = pack_bf16(f[4], f[5]);
    hf.u.w = pack_bf16(f[6], f[7]);
    short8 bw = W1f[kc * 64 + lane];
    acc2 = __builtin_amdgcn_mfma_f32_16x16x32_bf16(hf.s, bw, acc2, 0, 0, 0);
  }
#pragma unroll
  for (int r = 0; r < 4; r++) {
    int rr = rb + quad * 4 + r;
    if (rr < NU) P[(size_t)rr * DOUT + l16] = acc2[r];
  }
}

// ---------------- fused output: mean over uu of P_uu + mean over iu of P_iu ----------------
__global__ __launch_bounds__(256) void out_kernel(const float* __restrict__ P_uu,
                                                  const float* __restrict__ P_iu,
                                                  const int* __restrict__ off_uu,
                                                  const int* __restrict__ s_uu,
                                                  const int* __restrict__ off_iu,
                                                  const int* __restrict__ s_iu,
                                                  float* __restrict__ out) {
  int node = blockIdx.x * 4 + (threadIdx.x >> 6);
  if (node >= NU) return;
  int lane = threadIdx.x & 63;
  int sub = lane >> 4, elem = lane & 15;
  float a = 0.f, b = 0.f;
  int s0 = off_uu[node], s1 = off_uu[node + 1];
  for (int e = s0 + sub; e < s1; e += 4) a += P_uu[(size_t)s_uu[e] * DOUT + elem];
  int t0 = off_iu[node], t1 = off_iu[node + 1];
  for (int e = t0 + sub; e < t1; e += 4) b += P_iu[(size_t)s_iu[e] * DOUT + elem];
  float r = a * (1.0f / fmaxf((float)(s1 - s0), 1.0f)) +
            b * (1.0f / fmaxf((float)(t1 - t0), 1.0f));
  r += __shfl_xor(r, 16, 64);
  r += __shfl_xor(r, 32, 64);
  if (lane < 16) out[(size_t)node * DOUT + elem] = r;
}

extern "C" void kernel_launch(void* const* d_in, const int* in_sizes, int n_in,
                              void* d_out, int out_size, void* d_ws, size_t ws_size,
                              hipStream_t stream) {
  (void)in_sizes; (void)n_in; (void)out_size; (void)ws_size;
  const float* embed_user = (const float*)d_in[0];
  const float* embed_item = (const float*)d_in[1];
  const int* src_uu = (const int*)d_in[2];
  const int* dst_uu = (const int*)d_in[3];
  const int* src_ui = (const int*)d_in[4];
  const int* dst_ui = (const int*)d_in[5];
  const int* src_iu = (const int*)d_in[6];
  const int* dst_iu = (const int*)d_in[7];
  const float* W0_uu = (const float*)d_in[8];
  const float* b0_uu = (const float*)d_in[9];
  const float* W0_ui = (const float*)d_in[10];
  const float* b0_ui = (const float*)d_in[11];
  const float* W0_iu = (const float*)d_in[12];
  const float* b0_iu = (const float*)d_in[13];
  const float* W1_uu = (const float*)d_in[14];
  const float* b1_uu = (const float*)d_in[15];
  const float* W1_iu = (const float*)d_in[18];
  const float* b1_iu = (const float*)d_in[19];
  float* out = (float*)d_out;

  // ---- workspace layout (4-byte word offsets), total ~99.3 MB ----
  char* ws = (char*)d_ws;
  __hip_bfloat16* A_ui = (__hip_bfloat16*)(ws);                       // NPAD*128 bf16
  __hip_bfloat16* A_uu = (__hip_bfloat16*)(ws + 6402048ull * 4);
  __hip_bfloat16* A_iu = (__hip_bfloat16*)(ws + 12804096ull * 4);
  float* P_iu = (float*)(ws + 19206144ull * 4);                       // 1.6M f
  float* P_uu = (float*)(ws + 20806144ull * 4);
  short* pW0_uu = (short*)(ws + 22406144ull * 4);                     // 16384 bf16 each
  short* pW0_ui = (short*)(ws + 22414336ull * 4);
  short* pW0_iu = (short*)(ws + 22422528ull * 4);
  short* pW1_uu = (short*)(ws + 22430720ull * 4);                     // 2048 bf16 each
  short* pW1_iu = (short*)(ws + 22431744ull * 4);
  int* off_uu = (int*)(ws + 22432768ull * 4);                         // 100016 each
  int* off_iu = (int*)(ws + 22532784ull * 4);
  int* off_ui = (int*)(ws + 22632800ull * 4);
  int* cur = (int*)(ws + 22732816ull * 4);                            // 300000
  int* ssrc_uu = (int*)(ws + 23032816ull * 4);                        // 600000 each
  int* ssrc_iu = (int*)(ws + 23632816ull * 4);
  int* ssrc_ui = (int*)(ws + 24232816ull * 4);

  hipMemsetAsync(off_uu, 0, 300048ull * 4, stream);

  repack_kernel<<<(53248 + 255) / 256, 256, 0, stream>>>(
      W0_uu, W0_ui, W0_iu, W1_uu, W1_iu, pW0_uu, pW0_ui, pW0_iu, pW1_uu, pW1_iu);

  const int eb = (NEDGE + 255) / 256;
  hist3_kernel<<<3 * eb, 256, 0, stream>>>(dst_uu, dst_iu, dst_ui, off_uu, off_iu, off_ui, eb);
  scan3_kernel<<<3, 1024, 0, stream>>>(off_uu, off_iu, off_ui, NU + 1);
  curinit_kernel<<<(3 * NU + 255) / 256, 256, 0, stream>>>(cur, off_uu, off_iu, off_ui);
  scatter3_kernel<<<3 * eb, 256, 0, stream>>>(src_uu, dst_uu, src_iu, dst_iu, src_ui, dst_ui,
                                              cur, ssrc_uu, ssrc_iu, ssrc_ui, eb);

  const int nb1 = NPAD / 4;  // 25008 blocks per etype
  agg3_kernel<<<3 * nb1, 256, 0, stream>>>(embed_user, embed_item, off_ui, off_uu, off_iu,
                                           ssrc_ui, ssrc_uu, ssrc_iu,
                                           (__hip_bfloat162*)A_ui, (__hip_bfloat162*)A_uu,
                                           (__hip_bfloat162*)A_iu, nb1);

  const int nbi = NPAD / 64;  // 1563 row-blocks per path
  rows_mfma_kernel<<<2 * nbi, 256, 0, stream>>>(A_ui, A_uu, A_iu, off_ui, off_uu, off_iu,
                                                pW0_ui, pW0_uu, pW0_iu, b0_ui, b0_uu, b0_iu,
                                                pW1_iu, pW1_uu, b1_iu, b1_uu, P_iu, P_uu, nbi);

  out_kernel<<<(NU + 3) / 4, 256, 0, stream>>>(P_uu, P_iu, off_uu, ssrc_uu, off_iu, ssrc_iu, out);
}

// Round 3
// 594.243 us; speedup vs baseline: 1.5836x; 1.1732x over previous
//
#include <hip/hip_runtime.h>
#include <hip/hip_bf16.h>

#define NU 100000
#define NI 100000
#define NEDGE 600000
#define DIN 128
#define DOUT 16
#define NPAD 100032   // 1563 * 64
#define NCH 25        // scan chunks per etype (25 * 4096 >= 100001)

typedef __attribute__((ext_vector_type(8))) short short8;
typedef __attribute__((ext_vector_type(4))) float f32x4;

// ---- workspace word offsets ----
#define W_EU   0ull          // 6,400,000 w bf16 user table; P_iu@0, P_uu@1.6M alias after agg
#define W_AUI  6400000ull    // 6,402,048 w each A buffer; cur aliases A_ui head
#define W_AUU  12802048ull
#define W_AIU  19204096ull
#define W_PW   25606144ull   // packed weights, 26,624 w
#define W_OFFU 25632768ull   // 100,016 w each
#define W_OFFI 25732784ull
#define W_OFFX 25832800ull
#define W_SUU  25932816ull   // 600,000 w each
#define W_SIU  26532816ull
#define W_SUI  27132816ull
#define W_PART 27732816ull   // 128 w
#define W_EI   27732944ull   // 6,400,000 w (optional)
#define WS_FULL_BYTES (34132944ull * 4)

__device__ inline unsigned pack_bf16(float x, float y) {
  __hip_bfloat162 h = __float22bfloat162_rn(make_float2(x, y));
  unsigned u;
  __builtin_memcpy(&u, &h, 4);
  return u;
}

__device__ inline short bf16_bits(float x) {
  __hip_bfloat16 h = __float2bfloat16(x);
  short s;
  __builtin_memcpy(&s, &h, 2);
  return s;
}

__device__ inline void bf2_acc(unsigned u, float& ax, float& ay) {
  unsigned lo = u << 16, hi = u & 0xffff0000u;
  float f0, f1;
  __builtin_memcpy(&f0, &lo, 4);
  __builtin_memcpy(&f1, &hi, 4);
  ax += f0;
  ay += f1;
}

// ---------------- prep: embed->bf16 convert + hist + weight repack ----------------
__global__ __launch_bounds__(256) void prep_kernel(
    const float* __restrict__ Eu, const float* __restrict__ Ei,
    unsigned* __restrict__ Eu_b, unsigned* __restrict__ Ei_b,
    const int* __restrict__ d_uu, const int* __restrict__ d_iu, const int* __restrict__ d_ui,
    int* __restrict__ off_uu, int* __restrict__ off_iu, int* __restrict__ off_ui,
    const float* __restrict__ W0_uu, const float* __restrict__ W0_ui,
    const float* __restrict__ W0_iu, const float* __restrict__ W1_uu,
    const float* __restrict__ W1_iu, short* __restrict__ pW0_uu, short* __restrict__ pW0_ui,
    short* __restrict__ pW0_iu, short* __restrict__ pW1_uu, short* __restrict__ pW1_iu,
    int nconvU, int nconvI) {
  int b = blockIdx.x;
  if (b < nconvU + nconvI) {
    const float* src;
    unsigned* dst;
    int t;
    if (b < nconvU) { src = Eu; dst = Eu_b; t = b * 256 + threadIdx.x; }
    else { src = Ei; dst = Ei_b; t = (b - nconvU) * 256 + threadIdx.x; }
    const float4* s4 = (const float4*)src;
    float4 x = s4[(size_t)t * 2], y = s4[(size_t)t * 2 + 1];
    uint4 o;
    o.x = pack_bf16(x.x, x.y);
    o.y = pack_bf16(x.z, x.w);
    o.z = pack_bf16(y.x, y.y);
    o.w = pack_bf16(y.z, y.w);
    ((uint4*)dst)[t] = o;
    return;
  }
  b -= nconvU + nconvI;
  if (b < 3 * 2344) {
    int seg = b / 2344;
    int e = (b % 2344) * 256 + threadIdx.x;
    if (e >= NEDGE) return;
    const int* d = (seg == 0) ? d_uu : (seg == 1) ? d_iu : d_ui;
    int* off = (seg == 0) ? off_uu : (seg == 1) ? off_iu : off_ui;
    atomicAdd(&off[d[e] + 1], 1);
    return;
  }
  b -= 3 * 2344;
  int t = b * 256 + threadIdx.x;
  const float* src;
  short* dst;
  int base;
  bool w1 = false;
  if (t < 16384) { src = W0_uu; dst = pW0_uu; base = t; }
  else if (t < 32768) { src = W0_ui; dst = pW0_ui; base = t - 16384; }
  else if (t < 49152) { src = W0_iu; dst = pW0_iu; base = t - 32768; }
  else if (t < 51200) { src = W1_uu; dst = pW1_uu; base = t - 49152; w1 = true; }
  else if (t < 53248) { src = W1_iu; dst = pW1_iu; base = t - 51200; w1 = true; }
  else return;
  int j = base & 7;
  int lane = (base >> 3) & 63;
  int frag = base >> 9;
  int quad = lane >> 4, l16 = lane & 15;
  float val;
  if (!w1) {
    int kc = frag >> 3, nt = frag & 7;
    val = src[(kc * 32 + quad * 8 + j) * 128 + nt * 16 + l16];
  } else {
    int kc = frag;
    val = src[(kc * 32 + quad * 8 + j) * 16 + l16];
  }
  dst[base] = bf16_bits(val);
}

// ---------------- 3-phase parallel scan over the 3 histogram arrays ----------------
__global__ __launch_bounds__(1024) void scanA_kernel(int* __restrict__ off_uu,
                                                     int* __restrict__ off_iu,
                                                     int* __restrict__ off_ui,
                                                     int* __restrict__ partials) {
  int t = blockIdx.x / NCH, c = blockIdx.x % NCH;
  int* off = (t == 0) ? off_uu : (t == 1) ? off_iu : off_ui;
  const int n = NU + 1;
  __shared__ int wls[16];
  int tid = threadIdx.x, lane = tid & 63, wv = tid >> 6;
  int base = c * 4096 + tid * 4;
  int v0 = 0, v1 = 0, v2 = 0, v3 = 0;
  if (base + 3 < n) {
    v0 = off[base]; v1 = off[base + 1]; v2 = off[base + 2]; v3 = off[base + 3];
  } else {
    if (base < n) v0 = off[base];
    if (base + 1 < n) v1 = off[base + 1];
    if (base + 2 < n) v2 = off[base + 2];
  }
  int a0 = v0, a1 = a0 + v1, a2 = a1 + v2, a3 = a2 + v3;
  int s = a3, x = s;
#pragma unroll
  for (int d = 1; d < 64; d <<= 1) {
    int y = __shfl_up(x, d, 64);
    if (lane >= d) x += y;
  }
  if (lane == 63) wls[wv] = x;
  __syncthreads();
  if (wv == 0 && lane < 16) {
    int tt = wls[lane];
#pragma unroll
    for (int d = 1; d < 16; d <<= 1) {
      int y = __shfl_up(tt, d, 16);
      if ((lane & 15) >= d) tt += y;
    }
    wls[lane] = tt;
  }
  __syncthreads();
  int excl = x - s + (wv > 0 ? wls[wv - 1] : 0);
  if (base < n) off[base] = a0 + excl;
  if (base + 1 < n) off[base + 1] = a1 + excl;
  if (base + 2 < n) off[base + 2] = a2 + excl;
  if (base + 3 < n) off[base + 3] = a3 + excl;
  if (tid == 1023) partials[t * NCH + c] = wls[15];
}

__global__ void scanB_kernel(int* __restrict__ partials) {
  int wv = threadIdx.x >> 6, lane = threadIdx.x & 63;
  if (wv < 3 && lane < 32) {
    int x = (lane < NCH) ? partials[wv * NCH + lane] : 0;
#pragma unroll
    for (int d = 1; d < 32; d <<= 1) {
      int y = __shfl_up(x, d, 32);
      if ((lane & 31) >= d) x += y;
    }
    if (lane < NCH) partials[wv * NCH + lane] = x;
  }
}

__global__ __launch_bounds__(1024) void scanC_kernel(int* __restrict__ off_uu,
                                                     int* __restrict__ off_iu,
                                                     int* __restrict__ off_ui,
                                                     int* __restrict__ cur,
                                                     const int* __restrict__ partials) {
  int t = blockIdx.x / NCH, c = blockIdx.x % NCH;
  int* off = (t == 0) ? off_uu : (t == 1) ? off_iu : off_ui;
  int* curp = cur + t * NU;
  int prefix = (c > 0) ? partials[t * NCH + c - 1] : 0;
  int base = c * 4096 + threadIdx.x * 4;
#pragma unroll
  for (int j = 0; j < 4; j++) {
    int i = base + j;
    if (i <= NU) {
      int v = off[i] + prefix;
      off[i] = v;
      if (i < NU) curp[i] = v;
    }
  }
}

__global__ void scatter3_kernel(const int* __restrict__ s_uu, const int* __restrict__ d_uu,
                                const int* __restrict__ s_iu, const int* __restrict__ d_iu,
                                const int* __restrict__ s_ui, const int* __restrict__ d_ui,
                                int* __restrict__ cur, int* __restrict__ ssrc_uu,
                                int* __restrict__ ssrc_iu, int* __restrict__ ssrc_ui, int eb) {
  int seg = blockIdx.x / eb;
  int e = (blockIdx.x % eb) * 256 + threadIdx.x;
  if (e >= NEDGE) return;
  const int* src = (seg == 0) ? s_uu : (seg == 1) ? s_iu : s_ui;
  const int* dst = (seg == 0) ? d_uu : (seg == 1) ? d_iu : d_ui;
  int* curp = cur + seg * NU;
  int* out = (seg == 0) ? ssrc_uu : (seg == 1) ? ssrc_iu : ssrc_ui;
  int pos = atomicAdd(&curp[dst[e]], 1);
  out[pos] = src[e];
}

// ---------------- segment mean (3 etypes): bf16 gather -> bf16 rows ----------------
// seg0: ui (gather Xu), seg1: uu (gather Xu), seg2: iu (gather Xi, fp32 or bf16)
__global__ __launch_bounds__(256) void agg3_kernel(
    const unsigned* __restrict__ Xu, const void* __restrict__ Xi, int xi_bf16,
    const int* __restrict__ off_ui, const int* __restrict__ off_uu, const int* __restrict__ off_iu,
    const int* __restrict__ s_ui, const int* __restrict__ s_uu, const int* __restrict__ s_iu,
    unsigned* __restrict__ A_ui, unsigned* __restrict__ A_uu, unsigned* __restrict__ A_iu,
    int nb1) {
  int seg = blockIdx.x / nb1;
  int node = (blockIdx.x % nb1) * 4 + (threadIdx.x >> 6);
  int lane = threadIdx.x & 63;
  const int* off;
  const int* ss;
  unsigned* A;
  if (seg == 0) { off = off_ui; ss = s_ui; A = A_ui; }
  else if (seg == 1) { off = off_uu; ss = s_uu; A = A_uu; }
  else { off = off_iu; ss = s_iu; A = A_iu; }
  if (node >= NPAD) return;
  float ax = 0.f, ay = 0.f;
  int deg = 0;
  if (node < NU) {
    int s0 = off[node], s1 = off[node + 1];
    deg = s1 - s0;
    if (seg < 2 || xi_bf16) {
      const unsigned* X = (seg < 2) ? Xu : (const unsigned*)Xi;
      int e = s0;
      for (; e + 4 <= s1; e += 4) {
        int sa = ss[e], sb = ss[e + 1], sc = ss[e + 2], sd = ss[e + 3];
        unsigned ua = X[(size_t)sa * 64 + lane];
        unsigned ub = X[(size_t)sb * 64 + lane];
        unsigned uc = X[(size_t)sc * 64 + lane];
        unsigned ud = X[(size_t)sd * 64 + lane];
        bf2_acc(ua, ax, ay);
        bf2_acc(ub, ax, ay);
        bf2_acc(uc, ax, ay);
        bf2_acc(ud, ax, ay);
      }
      for (; e < s1; e++) {
        unsigned u = X[(size_t)ss[e] * 64 + lane];
        bf2_acc(u, ax, ay);
      }
    } else {
      const float* Xf = (const float*)Xi;
      int e = s0;
      for (; e + 4 <= s1; e += 4) {
        int sa = ss[e], sb = ss[e + 1], sc = ss[e + 2], sd = ss[e + 3];
        float2 va = *(const float2*)(Xf + (size_t)sa * DIN + lane * 2);
        float2 vb = *(const float2*)(Xf + (size_t)sb * DIN + lane * 2);
        float2 vc = *(const float2*)(Xf + (size_t)sc * DIN + lane * 2);
        float2 vd = *(const float2*)(Xf + (size_t)sd * DIN + lane * 2);
        ax += (va.x + vb.x) + (vc.x + vd.x);
        ay += (va.y + vb.y) + (vc.y + vd.y);
      }
      for (; e < s1; e++) {
        float2 v = *(const float2*)(Xf + (size_t)ss[e] * DIN + lane * 2);
        ax += v.x;
        ay += v.y;
      }
    }
  }
  float inv = 1.0f / fmaxf((float)deg, 1.0f);
  A[(size_t)node * 64 + lane] = pack_bf16(ax * inv, ay * inv);
}

// ---------------- fused MFMA rows ----------------
__global__ __launch_bounds__(256) void rows_mfma_kernel(
    const __hip_bfloat16* __restrict__ A_ui, const __hip_bfloat16* __restrict__ A_uu,
    const __hip_bfloat16* __restrict__ A_iu, const int* __restrict__ off_ui,
    const int* __restrict__ off_uu, const int* __restrict__ off_iu,
    const short* __restrict__ pW0_ui, const short* __restrict__ pW0_uu,
    const short* __restrict__ pW0_iu, const float* __restrict__ b0_ui,
    const float* __restrict__ b0_uu, const float* __restrict__ b0_iu,
    const short* __restrict__ pW1_iu, const short* __restrict__ pW1_uu,
    const float* __restrict__ b1_iu, const float* __restrict__ b1_uu,
    float* __restrict__ P_iu, float* __restrict__ P_uu, int nbi) {
  __shared__ float hs[4][2560];  // per-wave h staging: [col][row] fp32, row-pad 20

  const int tid = threadIdx.x;
  const int w = tid >> 6, lane = tid & 63;
  const int quad = lane >> 4, l16 = lane & 15;
  const bool user = (int)blockIdx.x >= nbi;
  const int blk = user ? (int)blockIdx.x - nbi : (int)blockIdx.x;
  const int rb = blk * 64 + w * 16;

  const __hip_bfloat16* A0 = user ? A_uu : A_ui;
  const int* off0 = user ? off_uu : off_ui;
  const short* W0a = user ? pW0_uu : pW0_ui;
  const float* b0a = user ? b0_uu : b0_ui;
  const short* W1p = user ? pW1_uu : pW1_iu;
  const float* b1v = user ? b1_uu : b1_iu;
  float* P = user ? P_uu : P_iu;

  float m0[4], m1[4];
#pragma unroll
  for (int r = 0; r < 4; r++) {
    int rr = rb + quad * 4 + r;
    m0[r] = 0.f;
    m1[r] = 0.f;
    if (rr < NU) {
      m0[r] = (off0[rr + 1] > off0[rr]) ? 1.f : 0.f;
      if (user) m1[r] = (off_iu[rr + 1] > off_iu[rr]) ? 1.f : 0.f;
    }
  }

  f32x4 acc[8];
#pragma unroll
  for (int nt = 0; nt < 8; nt++) {
    float ba = b0a[nt * 16 + l16];
    float bb = user ? b0_iu[nt * 16 + l16] : 0.f;
#pragma unroll
    for (int r = 0; r < 4; r++) acc[nt][r] = ba * m0[r] + bb * m1[r];
  }

  const short8* A0v = (const short8*)(A0 + (size_t)(rb + l16) * DIN);
  const short8* A1v = (const short8*)(A_iu + (size_t)(rb + l16) * DIN);
  const short8* B0p = (const short8*)W0a;
  const short8* B1p = (const short8*)pW0_iu;

#pragma unroll
  for (int kc = 0; kc < 4; kc++) {
    short8 a0 = A0v[kc * 4 + quad];
    short8 a1 = user ? A1v[kc * 4 + quad] : a0;
#pragma unroll
    for (int nt = 0; nt < 8; nt++) {
      short8 b0 = B0p[(kc * 8 + nt) * 64 + lane];
      acc[nt] = __builtin_amdgcn_mfma_f32_16x16x32_bf16(a0, b0, acc[nt], 0, 0, 0);
      if (user) {
        short8 bb = B1p[(kc * 8 + nt) * 64 + lane];
        acc[nt] = __builtin_amdgcn_mfma_f32_16x16x32_bf16(a1, bb, acc[nt], 0, 0, 0);
      }
    }
  }

  float* hw = &hs[w][0];
#pragma unroll
  for (int nt = 0; nt < 8; nt++) {
    int col = nt * 16 + l16;
    float4 v;
    v.x = fmaxf(acc[nt][0], 0.f);
    v.y = fmaxf(acc[nt][1], 0.f);
    v.z = fmaxf(acc[nt][2], 0.f);
    v.w = fmaxf(acc[nt][3], 0.f);
    *(float4*)&hw[col * 20 + quad * 4] = v;
  }
  __syncthreads();

  f32x4 acc2;
  {
    float bv = b1v[l16];
    acc2[0] = bv; acc2[1] = bv; acc2[2] = bv; acc2[3] = bv;
  }
  const short8* W1f = (const short8*)W1p;
#pragma unroll
  for (int kc = 0; kc < 4; kc++) {
    float f[8];
#pragma unroll
    for (int j = 0; j < 8; j++) f[j] = hw[(kc * 32 + quad * 8 + j) * 20 + l16];
    union { uint4 u; short8 s; } hf;
    hf.u.x = pack_bf16(f[0], f[1]);
    hf.u.y = pack_bf16(f[2], f[3]);
    hf.u.z = pack_bf16(f[4], f[5]);
    hf.u.w = pack_bf16(f[6], f[7]);
    short8 bw = W1f[kc * 64 + lane];
    acc2 = __builtin_amdgcn_mfma_f32_16x16x32_bf16(hf.s, bw, acc2, 0, 0, 0);
  }
#pragma unroll
  for (int r = 0; r < 4; r++) {
    int rr = rb + quad * 4 + r;
    if (rr < NU) P[(size_t)rr * DOUT + l16] = acc2[r];
  }
}

// ---------------- fused output ----------------
__global__ __launch_bounds__(256) void out_kernel(const float* __restrict__ P_uu,
                                                  const float* __restrict__ P_iu,
                                                  const int* __restrict__ off_uu,
                                                  const int* __restrict__ s_uu,
                                                  const int* __restrict__ off_iu,
                                                  const int* __restrict__ s_iu,
                                                  float* __restrict__ out) {
  int node = blockIdx.x * 4 + (threadIdx.x >> 6);
  if (node >= NU) return;
  int lane = threadIdx.x & 63;
  int sub = lane >> 4, elem = lane & 15;
  float a = 0.f, b = 0.f;
  int s0 = off_uu[node], s1 = off_uu[node + 1];
  for (int e = s0 + sub; e < s1; e += 4) a += P_uu[(size_t)s_uu[e] * DOUT + elem];
  int t0 = off_iu[node], t1 = off_iu[node + 1];
  for (int e = t0 + sub; e < t1; e += 4) b += P_iu[(size_t)s_iu[e] * DOUT + elem];
  float r = a * (1.0f / fmaxf((float)(s1 - s0), 1.0f)) +
            b * (1.0f / fmaxf((float)(t1 - t0), 1.0f));
  r += __shfl_xor(r, 16, 64);
  r += __shfl_xor(r, 32, 64);
  if (lane < 16) out[(size_t)node * DOUT + elem] = r;
}

extern "C" void kernel_launch(void* const* d_in, const int* in_sizes, int n_in,
                              void* d_out, int out_size, void* d_ws, size_t ws_size,
                              hipStream_t stream) {
  (void)in_sizes; (void)n_in; (void)out_size;
  const float* embed_user = (const float*)d_in[0];
  const float* embed_item = (const float*)d_in[1];
  const int* src_uu = (const int*)d_in[2];
  const int* dst_uu = (const int*)d_in[3];
  const int* src_ui = (const int*)d_in[4];
  const int* dst_ui = (const int*)d_in[5];
  const int* src_iu = (const int*)d_in[6];
  const int* dst_iu = (const int*)d_in[7];
  const float* W0_uu = (const float*)d_in[8];
  const float* b0_uu = (const float*)d_in[9];
  const float* W0_ui = (const float*)d_in[10];
  const float* b0_ui = (const float*)d_in[11];
  const float* W0_iu = (const float*)d_in[12];
  const float* b0_iu = (const float*)d_in[13];
  const float* W1_uu = (const float*)d_in[14];
  const float* b1_uu = (const float*)d_in[15];
  const float* W1_iu = (const float*)d_in[18];
  const float* b1_iu = (const float*)d_in[19];
  float* out = (float*)d_out;

  char* ws = (char*)d_ws;
  unsigned* Eu_b = (unsigned*)(ws + W_EU * 4);
  unsigned* A_ui = (unsigned*)(ws + W_AUI * 4);
  unsigned* A_uu = (unsigned*)(ws + W_AUU * 4);
  unsigned* A_iu = (unsigned*)(ws + W_AIU * 4);
  short* pW0_uu = (short*)(ws + W_PW * 4);
  short* pW0_ui = pW0_uu + 16384;
  short* pW0_iu = pW0_uu + 32768;
  short* pW1_uu = pW0_uu + 49152;
  short* pW1_iu = pW0_uu + 51200;
  int* off_uu = (int*)(ws + W_OFFU * 4);
  int* off_iu = (int*)(ws + W_OFFI * 4);
  int* off_ui = (int*)(ws + W_OFFX * 4);
  int* ssrc_uu = (int*)(ws + W_SUU * 4);
  int* ssrc_iu = (int*)(ws + W_SIU * 4);
  int* ssrc_ui = (int*)(ws + W_SUI * 4);
  int* partials = (int*)(ws + W_PART * 4);
  unsigned* Ei_b = (unsigned*)(ws + W_EI * 4);
  int* cur = (int*)A_ui;            // dead before agg3 writes A_ui
  float* P_iu = (float*)Eu_b;       // Eu_b dead after agg3
  float* P_uu = P_iu + 1600000;

  const int full = (ws_size >= WS_FULL_BYTES) ? 1 : 0;
  const int nconvU = 6250, nconvI = full ? 6250 : 0;
  const void* Xi = full ? (const void*)Ei_b : (const void*)embed_item;

  // zero the 3 histogram arrays (contiguous span)
  hipMemsetAsync(off_uu, 0, 300048ull * 4, stream);

  prep_kernel<<<nconvU + nconvI + 3 * 2344 + 208, 256, 0, stream>>>(
      embed_user, embed_item, Eu_b, Ei_b, dst_uu, dst_iu, dst_ui, off_uu, off_iu, off_ui,
      W0_uu, W0_ui, W0_iu, W1_uu, W1_iu, pW0_uu, pW0_ui, pW0_iu, pW1_uu, pW1_iu,
      nconvU, nconvI);

  scanA_kernel<<<3 * NCH, 1024, 0, stream>>>(off_uu, off_iu, off_ui, partials);
  scanB_kernel<<<1, 256, 0, stream>>>(partials);
  scanC_kernel<<<3 * NCH, 1024, 0, stream>>>(off_uu, off_iu, off_ui, cur, partials);

  const int eb = (NEDGE + 255) / 256;
  scatter3_kernel<<<3 * eb, 256, 0, stream>>>(src_uu, dst_uu, src_iu, dst_iu, src_ui, dst_ui,
                                              cur, ssrc_uu, ssrc_iu, ssrc_ui, eb);

  const int nb1 = NPAD / 4;
  agg3_kernel<<<3 * nb1, 256, 0, stream>>>(Eu_b, Xi, full, off_ui, off_uu, off_iu,
                                           ssrc_ui, ssrc_uu, ssrc_iu, A_ui, A_uu, A_iu, nb1);

  const int nbi = NPAD / 64;
  rows_mfma_kernel<<<2 * nbi, 256, 0, stream>>>(
      (const __hip_bfloat16*)A_ui, (const __hip_bfloat16*)A_uu, (const __hip_bfloat16*)A_iu,
      off_ui, off_uu, off_iu, pW0_ui, pW0_uu, pW0_iu, b0_ui, b0_uu, b0_iu,
      pW1_iu, pW1_uu, b1_iu, b1_uu, P_iu, P_uu, nbi);

  out_kernel<<<(NU + 3) / 4, 256, 0, stream>>>(P_uu, P_iu, off_uu, ssrc_uu, off_iu, ssrc_iu, out);
}

// Round 4
// 507.473 us; speedup vs baseline: 1.8543x; 1.1710x over previous
//
#include <hip/hip_runtime.h>
#include <hip/hip_bf16.h>

#define NU 100000
#define NI 100000
#define NEDGE 600000
#define DIN 128
#define DOUT 16
#define NPAD 100032   // 1563 * 64
#define NCH 25        // scan chunks per etype (25 * 4096 >= 100001)
#define NBUCK 98      // coarse buckets: dst>>10
#define NSB 256       // coarse-sort blocks per etype
#define SCH 2344      // edges per coarse-sort block (256*2344 >= 600000)

typedef __attribute__((ext_vector_type(8))) short short8;
typedef __attribute__((ext_vector_type(4))) float f32x4;

// ---- workspace word offsets ----
#define W_EU   0ull          // 6,400,000 w bf16 user table; P_iu@0, P_uu@1.6M alias after agg
#define W_AUI  6400000ull    // 6,402,048 w each A buffer; pairs alias A_ui pre-agg
#define W_AUU  12802048ull   // M matrix aliases A_uu head pre-agg
#define W_AIU  19204096ull
#define W_PW   25606144ull   // packed weights, 26,624 w
#define W_OFFU 25632768ull   // 100,016 w each
#define W_OFFI 25732784ull
#define W_OFFX 25832800ull
#define W_SUU  25932816ull   // 600,000 w each
#define W_SIU  26532816ull
#define W_SUI  27132816ull
#define W_PART 27732816ull   // 128 w
#define W_EI   27732944ull   // 6,400,000 w (optional)
#define WS_FULL_BYTES (34132944ull * 4)

__device__ inline unsigned pack_bf16(float x, float y) {
  __hip_bfloat162 h = __float22bfloat162_rn(make_float2(x, y));
  unsigned u;
  __builtin_memcpy(&u, &h, 4);
  return u;
}

__device__ inline short bf16_bits(float x) {
  __hip_bfloat16 h = __float2bfloat16(x);
  short s;
  __builtin_memcpy(&s, &h, 2);
  return s;
}

__device__ inline void bf2_acc(unsigned u, float& ax, float& ay) {
  unsigned lo = u << 16, hi = u & 0xffff0000u;
  float f0, f1;
  __builtin_memcpy(&f0, &lo, 4);
  __builtin_memcpy(&f1, &hi, 4);
  ax += f0;
  ay += f1;
}

// ---------------- prep: embed->bf16 + fine hist + coarse count + weight repack ----------------
__global__ __launch_bounds__(256) void prep_kernel(
    const float* __restrict__ Eu, const float* __restrict__ Ei,
    unsigned* __restrict__ Eu_b, unsigned* __restrict__ Ei_b,
    const int* __restrict__ d_uu, const int* __restrict__ d_iu, const int* __restrict__ d_ui,
    int* __restrict__ off_uu, int* __restrict__ off_iu, int* __restrict__ off_ui,
    int* __restrict__ M,
    const float* __restrict__ W0_uu, const float* __restrict__ W0_ui,
    const float* __restrict__ W0_iu, const float* __restrict__ W1_uu,
    const float* __restrict__ W1_iu, short* __restrict__ pW0_uu, short* __restrict__ pW0_ui,
    short* __restrict__ pW0_iu, short* __restrict__ pW1_uu, short* __restrict__ pW1_iu,
    int nconvU, int nconvI) {
  __shared__ int h[128];
  int b = blockIdx.x;
  int tid = threadIdx.x;
  if (b < nconvU + nconvI) {
    const float* src;
    unsigned* dst;
    int t;
    if (b < nconvU) { src = Eu; dst = Eu_b; t = b * 256 + tid; }
    else { src = Ei; dst = Ei_b; t = (b - nconvU) * 256 + tid; }
    const float4* s4 = (const float4*)src;
    float4 x = s4[(size_t)t * 2], y = s4[(size_t)t * 2 + 1];
    uint4 o;
    o.x = pack_bf16(x.x, x.y);
    o.y = pack_bf16(x.z, x.w);
    o.z = pack_bf16(y.x, y.y);
    o.w = pack_bf16(y.z, y.w);
    ((uint4*)dst)[t] = o;
    return;
  }
  b -= nconvU + nconvI;
  if (b < 3 * 2344) {
    int seg = b / 2344;
    int e = (b % 2344) * 256 + tid;
    if (e >= NEDGE) return;
    const int* d = (seg == 0) ? d_uu : (seg == 1) ? d_iu : d_ui;
    int* off = (seg == 0) ? off_uu : (seg == 1) ? off_iu : off_ui;
    atomicAdd(&off[d[e] + 1], 1);
    return;
  }
  b -= 3 * 2344;
  if (b < 3 * NSB) {
    // coarse per-block bucket counts
    int t = b / NSB, k = b % NSB;
    if (tid < 128) h[tid] = 0;
    __syncthreads();
    const int* d = (t == 0) ? d_uu : (t == 1) ? d_iu : d_ui;
    int e0 = k * SCH, e1 = min(e0 + SCH, NEDGE);
    for (int e = e0 + tid; e < e1; e += 256) atomicAdd(&h[d[e] >> 10], 1);
    __syncthreads();
    if (tid < NBUCK) M[t * (NBUCK * NSB) + tid * NSB + k] = h[tid];
    return;
  }
  b -= 3 * NSB;
  int t = b * 256 + tid;
  const float* src;
  short* dst;
  int base;
  bool w1 = false;
  if (t < 16384) { src = W0_uu; dst = pW0_uu; base = t; }
  else if (t < 32768) { src = W0_ui; dst = pW0_ui; base = t - 16384; }
  else if (t < 49152) { src = W0_iu; dst = pW0_iu; base = t - 32768; }
  else if (t < 51200) { src = W1_uu; dst = pW1_uu; base = t - 49152; w1 = true; }
  else if (t < 53248) { src = W1_iu; dst = pW1_iu; base = t - 51200; w1 = true; }
  else return;
  int j = base & 7;
  int lane = (base >> 3) & 63;
  int frag = base >> 9;
  int quad = lane >> 4, l16 = lane & 15;
  float val;
  if (!w1) {
    int kc = frag >> 3, nt = frag & 7;
    val = src[(kc * 32 + quad * 8 + j) * 128 + nt * 16 + l16];
  } else {
    int kc = frag;
    val = src[(kc * 32 + quad * 8 + j) * 16 + l16];
  }
  dst[base] = bf16_bits(val);
}

// ---------------- 3-phase parallel scan over the 3 fine histograms ----------------
__global__ __launch_bounds__(1024) void scanA_kernel(int* __restrict__ off_uu,
                                                     int* __restrict__ off_iu,
                                                     int* __restrict__ off_ui,
                                                     int* __restrict__ partials) {
  int t = blockIdx.x / NCH, c = blockIdx.x % NCH;
  int* off = (t == 0) ? off_uu : (t == 1) ? off_iu : off_ui;
  const int n = NU + 1;
  __shared__ int wls[16];
  int tid = threadIdx.x, lane = tid & 63, wv = tid >> 6;
  int base = c * 4096 + tid * 4;
  int v0 = 0, v1 = 0, v2 = 0, v3 = 0;
  if (base + 3 < n) {
    v0 = off[base]; v1 = off[base + 1]; v2 = off[base + 2]; v3 = off[base + 3];
  } else {
    if (base < n) v0 = off[base];
    if (base + 1 < n) v1 = off[base + 1];
    if (base + 2 < n) v2 = off[base + 2];
  }
  int a0 = v0, a1 = a0 + v1, a2 = a1 + v2, a3 = a2 + v3;
  int s = a3, x = s;
#pragma unroll
  for (int d = 1; d < 64; d <<= 1) {
    int y = __shfl_up(x, d, 64);
    if (lane >= d) x += y;
  }
  if (lane == 63) wls[wv] = x;
  __syncthreads();
  if (wv == 0 && lane < 16) {
    int tt = wls[lane];
#pragma unroll
    for (int d = 1; d < 16; d <<= 1) {
      int y = __shfl_up(tt, d, 16);
      if ((lane & 15) >= d) tt += y;
    }
    wls[lane] = tt;
  }
  __syncthreads();
  int excl = x - s + (wv > 0 ? wls[wv - 1] : 0);
  if (base < n) off[base] = a0 + excl;
  if (base + 1 < n) off[base + 1] = a1 + excl;
  if (base + 2 < n) off[base + 2] = a2 + excl;
  if (base + 3 < n) off[base + 3] = a3 + excl;
  if (tid == 1023) partials[t * NCH + c] = wls[15];
}

__global__ void scanB_kernel(int* __restrict__ partials) {
  int wv = threadIdx.x >> 6, lane = threadIdx.x & 63;
  if (wv < 3 && lane < 32) {
    int x = (lane < NCH) ? partials[wv * NCH + lane] : 0;
#pragma unroll
    for (int d = 1; d < 32; d <<= 1) {
      int y = __shfl_up(x, d, 32);
      if ((lane & 31) >= d) x += y;
    }
    if (lane < NCH) partials[wv * NCH + lane] = x;
  }
}

__global__ __launch_bounds__(1024) void scanC_kernel(int* __restrict__ off_uu,
                                                     int* __restrict__ off_iu,
                                                     int* __restrict__ off_ui,
                                                     const int* __restrict__ partials) {
  int t = blockIdx.x / NCH, c = blockIdx.x % NCH;
  int* off = (t == 0) ? off_uu : (t == 1) ? off_iu : off_ui;
  int prefix = (c > 0) ? partials[t * NCH + c - 1] : 0;
  int base = c * 4096 + threadIdx.x * 4;
#pragma unroll
  for (int j = 0; j < 4; j++) {
    int i = base + j;
    if (i <= NU) off[i] += prefix;
  }
}

// ---------------- coarse-sort offsets: exclusive scan of M[b][:] + bucket base ----------------
__global__ __launch_bounds__(256) void scanM_kernel(int* __restrict__ M,
                                                    const int* __restrict__ off_uu,
                                                    const int* __restrict__ off_iu,
                                                    const int* __restrict__ off_ui) {
  int t = blockIdx.x / NBUCK, b = blockIdx.x % NBUCK;
  const int* off = (t == 0) ? off_uu : (t == 1) ? off_iu : off_ui;
  int* Mt = M + t * (NBUCK * NSB) + b * NSB;
  __shared__ int wls[4];
  int tid = threadIdx.x, lane = tid & 63, wv = tid >> 6;
  int v = Mt[tid];
  int x = v;
#pragma unroll
  for (int d = 1; d < 64; d <<= 1) {
    int y = __shfl_up(x, d, 64);
    if (lane >= d) x += y;
  }
  if (lane == 63) wls[wv] = x;
  __syncthreads();
  if (tid == 0) {
    int r = 0;
#pragma unroll
    for (int i = 0; i < 4; i++) { int tt = wls[i]; wls[i] = r; r += tt; }
  }
  __syncthreads();
  int boff = off[min(b << 10, NU)];
  Mt[tid] = boff + x + wls[wv] - v;  // exclusive + bucket base
}

// ---------------- coarse scatter: block-private dense pair writes ----------------
__global__ __launch_bounds__(256) void coarse_scatter_kernel(
    const int* __restrict__ s_uu, const int* __restrict__ d_uu,
    const int* __restrict__ s_iu, const int* __restrict__ d_iu,
    const int* __restrict__ s_ui, const int* __restrict__ d_ui,
    const int* __restrict__ M, uint2* __restrict__ pairs) {
  __shared__ int cur[NBUCK];
  int t = blockIdx.x / NSB, k = blockIdx.x % NSB;
  int tid = threadIdx.x;
  if (tid < NBUCK) cur[tid] = M[t * (NBUCK * NSB) + tid * NSB + k];
  __syncthreads();
  const int* src = (t == 0) ? s_uu : (t == 1) ? s_iu : s_ui;
  const int* dst = (t == 0) ? d_uu : (t == 1) ? d_iu : d_ui;
  uint2* pr = pairs + (size_t)t * NEDGE;
  int e0 = k * SCH, e1 = min(e0 + SCH, NEDGE);
  for (int e = e0 + tid; e < e1; e += 256) {
    int d = dst[e];
    int pos = atomicAdd(&cur[d >> 10], 1);
    pr[pos] = make_uint2((unsigned)src[e], (unsigned)d);
  }
}

// ---------------- fine CSR build: one block per bucket, LDS cursors ----------------
__global__ __launch_bounds__(256) void fine_sort_kernel(
    const uint2* __restrict__ pairs, const int* __restrict__ off_uu,
    const int* __restrict__ off_iu, const int* __restrict__ off_ui,
    int* __restrict__ ssrc_uu, int* __restrict__ ssrc_iu, int* __restrict__ ssrc_ui) {
  __shared__ int cur[1024];
  int t = blockIdx.x / NBUCK, b = blockIdx.x % NBUCK;
  int tid = threadIdx.x;
  const int* off = (t == 0) ? off_uu : (t == 1) ? off_iu : off_ui;
  int* ss = (t == 0) ? ssrc_uu : (t == 1) ? ssrc_iu : ssrc_ui;
  const uint2* pr = pairs + (size_t)t * NEDGE;
  int base = b << 10;
  int nn = min(1024, NU - base);
  for (int i = tid; i < nn; i += 256) cur[i] = off[base + i];
  __syncthreads();
  int lo = off[base], hi = off[base + nn];
  for (int e = lo + tid; e < hi; e += 256) {
    uint2 p = pr[e];
    int pos = atomicAdd(&cur[(int)p.y - base], 1);
    ss[pos] = (int)p.x;
  }
}

// ---------------- segment mean (3 etypes): bf16 gather -> bf16 rows ----------------
__global__ __launch_bounds__(256) void agg3_kernel(
    const unsigned* __restrict__ Xu, const void* __restrict__ Xi, int xi_bf16,
    const int* __restrict__ off_ui, const int* __restrict__ off_uu, const int* __restrict__ off_iu,
    const int* __restrict__ s_ui, const int* __restrict__ s_uu, const int* __restrict__ s_iu,
    unsigned* __restrict__ A_ui, unsigned* __restrict__ A_uu, unsigned* __restrict__ A_iu,
    int nb1) {
  int seg = blockIdx.x / nb1;
  int node = (blockIdx.x % nb1) * 4 + (threadIdx.x >> 6);
  int lane = threadIdx.x & 63;
  const int* off;
  const int* ss;
  unsigned* A;
  if (seg == 0) { off = off_ui; ss = s_ui; A = A_ui; }
  else if (seg == 1) { off = off_uu; ss = s_uu; A = A_uu; }
  else { off = off_iu; ss = s_iu; A = A_iu; }
  if (node >= NPAD) return;
  float ax = 0.f, ay = 0.f;
  int deg = 0;
  if (node < NU) {
    int s0 = off[node], s1 = off[node + 1];
    deg = s1 - s0;
    if (seg < 2 || xi_bf16) {
      const unsigned* X = (seg < 2) ? Xu : (const unsigned*)Xi;
      int e = s0;
      for (; e + 4 <= s1; e += 4) {
        int sa = ss[e], sb = ss[e + 1], sc = ss[e + 2], sd = ss[e + 3];
        unsigned ua = X[(size_t)sa * 64 + lane];
        unsigned ub = X[(size_t)sb * 64 + lane];
        unsigned uc = X[(size_t)sc * 64 + lane];
        unsigned ud = X[(size_t)sd * 64 + lane];
        bf2_acc(ua, ax, ay);
        bf2_acc(ub, ax, ay);
        bf2_acc(uc, ax, ay);
        bf2_acc(ud, ax, ay);
      }
      for (; e < s1; e++) {
        unsigned u = X[(size_t)ss[e] * 64 + lane];
        bf2_acc(u, ax, ay);
      }
    } else {
      const float* Xf = (const float*)Xi;
      int e = s0;
      for (; e + 4 <= s1; e += 4) {
        int sa = ss[e], sb = ss[e + 1], sc = ss[e + 2], sd = ss[e + 3];
        float2 va = *(const float2*)(Xf + (size_t)sa * DIN + lane * 2);
        float2 vb = *(const float2*)(Xf + (size_t)sb * DIN + lane * 2);
        float2 vc = *(const float2*)(Xf + (size_t)sc * DIN + lane * 2);
        float2 vd = *(const float2*)(Xf + (size_t)sd * DIN + lane * 2);
        ax += (va.x + vb.x) + (vc.x + vd.x);
        ay += (va.y + vb.y) + (vc.y + vd.y);
      }
      for (; e < s1; e++) {
        float2 v = *(const float2*)(Xf + (size_t)ss[e] * DIN + lane * 2);
        ax += v.x;
        ay += v.y;
      }
    }
  }
  float inv = 1.0f / fmaxf((float)deg, 1.0f);
  A[(size_t)node * 64 + lane] = pack_bf16(ax * inv, ay * inv);
}

// ---------------- fused MFMA rows ----------------
__global__ __launch_bounds__(256) void rows_mfma_kernel(
    const __hip_bfloat16* __restrict__ A_ui, const __hip_bfloat16* __restrict__ A_uu,
    const __hip_bfloat16* __restrict__ A_iu, const int* __restrict__ off_ui,
    const int* __restrict__ off_uu, const int* __restrict__ off_iu,
    const short* __restrict__ pW0_ui, const short* __restrict__ pW0_uu,
    const short* __restrict__ pW0_iu, const float* __restrict__ b0_ui,
    const float* __restrict__ b0_uu, const float* __restrict__ b0_iu,
    const short* __restrict__ pW1_iu, const short* __restrict__ pW1_uu,
    const float* __restrict__ b1_iu, const float* __restrict__ b1_uu,
    float* __restrict__ P_iu, float* __restrict__ P_uu, int nbi) {
  __shared__ float hs[4][2560];

  const int tid = threadIdx.x;
  const int w = tid >> 6, lane = tid & 63;
  const int quad = lane >> 4, l16 = lane & 15;
  const bool user = (int)blockIdx.x >= nbi;
  const int blk = user ? (int)blockIdx.x - nbi : (int)blockIdx.x;
  const int rb = blk * 64 + w * 16;

  const __hip_bfloat16* A0 = user ? A_uu : A_ui;
  const int* off0 = user ? off_uu : off_ui;
  const short* W0a = user ? pW0_uu : pW0_ui;
  const float* b0a = user ? b0_uu : b0_ui;
  const short* W1p = user ? pW1_uu : pW1_iu;
  const float* b1v = user ? b1_uu : b1_iu;
  float* P = user ? P_uu : P_iu;

  float m0[4], m1[4];
#pragma unroll
  for (int r = 0; r < 4; r++) {
    int rr = rb + quad * 4 + r;
    m0[r] = 0.f;
    m1[r] = 0.f;
    if (rr < NU) {
      m0[r] = (off0[rr + 1] > off0[rr]) ? 1.f : 0.f;
      if (user) m1[r] = (off_iu[rr + 1] > off_iu[rr]) ? 1.f : 0.f;
    }
  }

  f32x4 acc[8];
#pragma unroll
  for (int nt = 0; nt < 8; nt++) {
    float ba = b0a[nt * 16 + l16];
    float bb = user ? b0_iu[nt * 16 + l16] : 0.f;
#pragma unroll
    for (int r = 0; r < 4; r++) acc[nt][r] = ba * m0[r] + bb * m1[r];
  }

  const short8* A0v = (const short8*)(A0 + (size_t)(rb + l16) * DIN);
  const short8* A1v = (const short8*)(A_iu + (size_t)(rb + l16) * DIN);
  const short8* B0p = (const short8*)W0a;
  const short8* B1p = (const short8*)pW0_iu;

#pragma unroll
  for (int kc = 0; kc < 4; kc++) {
    short8 a0 = A0v[kc * 4 + quad];
    short8 a1 = user ? A1v[kc * 4 + quad] : a0;
#pragma unroll
    for (int nt = 0; nt < 8; nt++) {
      short8 b0 = B0p[(kc * 8 + nt) * 64 + lane];
      acc[nt] = __builtin_amdgcn_mfma_f32_16x16x32_bf16(a0, b0, acc[nt], 0, 0, 0);
      if (user) {
        short8 bb = B1p[(kc * 8 + nt) * 64 + lane];
        acc[nt] = __builtin_amdgcn_mfma_f32_16x16x32_bf16(a1, bb, acc[nt], 0, 0, 0);
      }
    }
  }

  float* hw = &hs[w][0];
#pragma unroll
  for (int nt = 0; nt < 8; nt++) {
    int col = nt * 16 + l16;
    float4 v;
    v.x = fmaxf(acc[nt][0], 0.f);
    v.y = fmaxf(acc[nt][1], 0.f);
    v.z = fmaxf(acc[nt][2], 0.f);
    v.w = fmaxf(acc[nt][3], 0.f);
    *(float4*)&hw[col * 20 + quad * 4] = v;
  }
  __syncthreads();

  f32x4 acc2;
  {
    float bv = b1v[l16];
    acc2[0] = bv; acc2[1] = bv; acc2[2] = bv; acc2[3] = bv;
  }
  const short8* W1f = (const short8*)W1p;
#pragma unroll
  for (int kc = 0; kc < 4; kc++) {
    float f[8];
#pragma unroll
    for (int j = 0; j < 8; j++) f[j] = hw[(kc * 32 + quad * 8 + j) * 20 + l16];
    union { uint4 u; short8 s; } hf;
    hf.u.x = pack_bf16(f[0], f[1]);
    hf.u.y = pack_bf16(f[2], f[3]);
    hf.u.z = pack_bf16(f[4], f[5]);
    hf.u.w = pack_bf16(f[6], f[7]);
    short8 bw = W1f[kc * 64 + lane];
    acc2 = __builtin_amdgcn_mfma_f32_16x16x32_bf16(hf.s, bw, acc2, 0, 0, 0);
  }
#pragma unroll
  for (int r = 0; r < 4; r++) {
    int rr = rb + quad * 4 + r;
    if (rr < NU) P[(size_t)rr * DOUT + l16] = acc2[r];
  }
}

// ---------------- fused output ----------------
__global__ __launch_bounds__(256) void out_kernel(const float* __restrict__ P_uu,
                                                  const float* __restrict__ P_iu,
                                                  const int* __restrict__ off_uu,
                                                  const int* __restrict__ s_uu,
                                                  const int* __restrict__ off_iu,
                                                  const int* __restrict__ s_iu,
                                                  float* __restrict__ out) {
  int node = blockIdx.x * 4 + (threadIdx.x >> 6);
  if (node >= NU) return;
  int lane = threadIdx.x & 63;
  int sub = lane >> 4, elem = lane & 15;
  float a = 0.f, b = 0.f;
  int s0 = off_uu[node], s1 = off_uu[node + 1];
  for (int e = s0 + sub; e < s1; e += 4) a += P_uu[(size_t)s_uu[e] * DOUT + elem];
  int t0 = off_iu[node], t1 = off_iu[node + 1];
  for (int e = t0 + sub; e < t1; e += 4) b += P_iu[(size_t)s_iu[e] * DOUT + elem];
  float r = a * (1.0f / fmaxf((float)(s1 - s0), 1.0f)) +
            b * (1.0f / fmaxf((float)(t1 - t0), 1.0f));
  r += __shfl_xor(r, 16, 64);
  r += __shfl_xor(r, 32, 64);
  if (lane < 16) out[(size_t)node * DOUT + elem] = r;
}

extern "C" void kernel_launch(void* const* d_in, const int* in_sizes, int n_in,
                              void* d_out, int out_size, void* d_ws, size_t ws_size,
                              hipStream_t stream) {
  (void)in_sizes; (void)n_in; (void)out_size;
  const float* embed_user = (const float*)d_in[0];
  const float* embed_item = (const float*)d_in[1];
  const int* src_uu = (const int*)d_in[2];
  const int* dst_uu = (const int*)d_in[3];
  const int* src_ui = (const int*)d_in[4];
  const int* dst_ui = (const int*)d_in[5];
  const int* src_iu = (const int*)d_in[6];
  const int* dst_iu = (const int*)d_in[7];
  const float* W0_uu = (const float*)d_in[8];
  const float* b0_uu = (const float*)d_in[9];
  const float* W0_ui = (const float*)d_in[10];
  const float* b0_ui = (const float*)d_in[11];
  const float* W0_iu = (const float*)d_in[12];
  const float* b0_iu = (const float*)d_in[13];
  const float* W1_uu = (const float*)d_in[14];
  const float* b1_uu = (const float*)d_in[15];
  const float* W1_iu = (const float*)d_in[18];
  const float* b1_iu = (const float*)d_in[19];
  float* out = (float*)d_out;

  char* ws = (char*)d_ws;
  unsigned* Eu_b = (unsigned*)(ws + W_EU * 4);
  unsigned* A_ui = (unsigned*)(ws + W_AUI * 4);
  unsigned* A_uu = (unsigned*)(ws + W_AUU * 4);
  unsigned* A_iu = (unsigned*)(ws + W_AIU * 4);
  short* pW0_uu = (short*)(ws + W_PW * 4);
  short* pW0_ui = pW0_uu + 16384;
  short* pW0_iu = pW0_uu + 32768;
  short* pW1_uu = pW0_uu + 49152;
  short* pW1_iu = pW0_uu + 51200;
  int* off_uu = (int*)(ws + W_OFFU * 4);
  int* off_iu = (int*)(ws + W_OFFI * 4);
  int* off_ui = (int*)(ws + W_OFFX * 4);
  int* ssrc_uu = (int*)(ws + W_SUU * 4);
  int* ssrc_iu = (int*)(ws + W_SIU * 4);
  int* ssrc_ui = (int*)(ws + W_SUI * 4);
  int* partials = (int*)(ws + W_PART * 4);
  unsigned* Ei_b = (unsigned*)(ws + W_EI * 4);
  uint2* pairs = (uint2*)A_ui;      // 3.6M w, dead before agg3 writes A_ui
  int* M = (int*)A_uu;              // 75,264 w, dead after coarse_scatter... (read until then)
  float* P_iu = (float*)Eu_b;       // Eu_b dead after agg3
  float* P_uu = P_iu + 1600000;

  const int full = (ws_size >= WS_FULL_BYTES) ? 1 : 0;
  const int nconvU = 6250, nconvI = full ? 6250 : 0;
  const void* Xi = full ? (const void*)Ei_b : (const void*)embed_item;

  hipMemsetAsync(off_uu, 0, 300048ull * 4, stream);

  prep_kernel<<<nconvU + nconvI + 3 * 2344 + 3 * NSB + 208, 256, 0, stream>>>(
      embed_user, embed_item, Eu_b, Ei_b, dst_uu, dst_iu, dst_ui, off_uu, off_iu, off_ui,
      M, W0_uu, W0_ui, W0_iu, W1_uu, W1_iu, pW0_uu, pW0_ui, pW0_iu, pW1_uu, pW1_iu,
      nconvU, nconvI);

  scanA_kernel<<<3 * NCH, 1024, 0, stream>>>(off_uu, off_iu, off_ui, partials);
  scanB_kernel<<<1, 256, 0, stream>>>(partials);
  scanC_kernel<<<3 * NCH, 1024, 0, stream>>>(off_uu, off_iu, off_ui, partials);

  scanM_kernel<<<3 * NBUCK, 256, 0, stream>>>(M, off_uu, off_iu, off_ui);
  coarse_scatter_kernel<<<3 * NSB, 256, 0, stream>>>(src_uu, dst_uu, src_iu, dst_iu,
                                                     src_ui, dst_ui, M, pairs);
  fine_sort_kernel<<<3 * NBUCK, 256, 0, stream>>>(pairs, off_uu, off_iu, off_ui,
                                                  ssrc_uu, ssrc_iu, ssrc_ui);

  const int nb1 = NPAD / 4;
  agg3_kernel<<<3 * nb1, 256, 0, stream>>>(Eu_b, Xi, full, off_ui, off_uu, off_iu,
                                           ssrc_ui, ssrc_uu, ssrc_iu, A_ui, A_uu, A_iu, nb1);

  const int nbi = NPAD / 64;
  rows_mfma_kernel<<<2 * nbi, 256, 0, stream>>>(
      (const __hip_bfloat16*)A_ui, (const __hip_bfloat16*)A_uu, (const __hip_bfloat16*)A_iu,
      off_ui, off_uu, off_iu, pW0_ui, pW0_uu, pW0_iu, b0_ui, b0_uu, b0_iu,
      pW1_iu, pW1_uu, b1_iu, b1_uu, P_iu, P_uu, nbi);

  out_kernel<<<(NU + 3) / 4, 256, 0, stream>>>(P_uu, P_iu, off_uu, ssrc_uu, off_iu, ssrc_iu, out);
}

// Round 5
// 467.450 us; speedup vs baseline: 2.0131x; 1.0856x over previous
//
#include <hip/hip_runtime.h>
#include <hip/hip_bf16.h>

#define NU 100000
#define NI 100000
#define NEDGE 600000
#define DIN 128
#define DOUT 16
#define NPAD 100032   // 1563 * 64; also 6252 * 16
#define NCH 25        // scan chunks per etype (25 * 4096 >= 100001)
#define BSH 9         // coarse bucket shift
#define NBUCK 196     // ceil(100000 / 512)
#define NSB 256       // coarse-sort blocks per etype
#define SCH 2344      // edges per coarse-sort block (256*2344 >= 600000)

typedef __attribute__((ext_vector_type(8))) short short8;
typedef __attribute__((ext_vector_type(4))) float f32x4;

// ---- workspace word offsets ----
#define W_EU   0ull          // 6,400,000 w bf16 user table; P_iu@0, P_uu@1.6M alias after agg
#define W_AUI  6400000ull    // 6,402,048 w each A buffer; pairs alias A_ui pre-agg
#define W_AUU  12802048ull   // M matrix aliases A_uu head pre-agg
#define W_AIU  19204096ull
#define W_PW   25606144ull   // packed weights, 26,624 w
#define W_OFFU 25632768ull   // 100,016 w each
#define W_OFFI 25732784ull
#define W_OFFX 25832800ull
#define W_SUU  25932816ull   // 600,000 w each
#define W_SIU  26532816ull
#define W_SUI  27132816ull
#define W_PART 27732816ull   // 128 w
#define W_EI   27732944ull   // 6,400,000 w (optional)
#define WS_FULL_BYTES (34132944ull * 4)

__device__ inline unsigned pack_bf16(float x, float y) {
  __hip_bfloat162 h = __float22bfloat162_rn(make_float2(x, y));
  unsigned u;
  __builtin_memcpy(&u, &h, 4);
  return u;
}

__device__ inline short bf16_bits(float x) {
  __hip_bfloat16 h = __float2bfloat16(x);
  short s;
  __builtin_memcpy(&s, &h, 2);
  return s;
}

__device__ inline void bf2_acc(unsigned u, float& ax, float& ay) {
  unsigned lo = u << 16, hi = u & 0xffff0000u;
  float f0, f1;
  __builtin_memcpy(&f0, &lo, 4);
  __builtin_memcpy(&f1, &hi, 4);
  ax += f0;
  ay += f1;
}

// ---------------- prep: embed->bf16 + fine hist + coarse count + weight repack ----------------
__global__ __launch_bounds__(256) void prep_kernel(
    const float* __restrict__ Eu, const float* __restrict__ Ei,
    unsigned* __restrict__ Eu_b, unsigned* __restrict__ Ei_b,
    const int* __restrict__ d_uu, const int* __restrict__ d_iu, const int* __restrict__ d_ui,
    int* __restrict__ off_uu, int* __restrict__ off_iu, int* __restrict__ off_ui,
    int* __restrict__ M,
    const float* __restrict__ W0_uu, const float* __restrict__ W0_ui,
    const float* __restrict__ W0_iu, const float* __restrict__ W1_uu,
    const float* __restrict__ W1_iu, short* __restrict__ pW0_uu, short* __restrict__ pW0_ui,
    short* __restrict__ pW0_iu, short* __restrict__ pW1_uu, short* __restrict__ pW1_iu,
    int nconvU, int nconvI) {
  __shared__ int h[NBUCK];
  int b = blockIdx.x;
  int tid = threadIdx.x;
  if (b < nconvU + nconvI) {
    const float* src;
    unsigned* dst;
    int t;
    if (b < nconvU) { src = Eu; dst = Eu_b; t = b * 256 + tid; }
    else { src = Ei; dst = Ei_b; t = (b - nconvU) * 256 + tid; }
    const float4* s4 = (const float4*)src;
    float4 x = s4[(size_t)t * 2], y = s4[(size_t)t * 2 + 1];
    uint4 o;
    o.x = pack_bf16(x.x, x.y);
    o.y = pack_bf16(x.z, x.w);
    o.z = pack_bf16(y.x, y.y);
    o.w = pack_bf16(y.z, y.w);
    ((uint4*)dst)[t] = o;
    return;
  }
  b -= nconvU + nconvI;
  if (b < 3 * 2344) {
    int seg = b / 2344;
    int e = (b % 2344) * 256 + tid;
    if (e >= NEDGE) return;
    const int* d = (seg == 0) ? d_uu : (seg == 1) ? d_iu : d_ui;
    int* off = (seg == 0) ? off_uu : (seg == 1) ? off_iu : off_ui;
    atomicAdd(&off[d[e] + 1], 1);
    return;
  }
  b -= 3 * 2344;
  if (b < 3 * NSB) {
    int t = b / NSB, k = b % NSB;
    if (tid < NBUCK) h[tid] = 0;
    __syncthreads();
    const int* d = (t == 0) ? d_uu : (t == 1) ? d_iu : d_ui;
    int e0 = k * SCH, e1 = min(e0 + SCH, NEDGE);
    for (int e = e0 + tid; e < e1; e += 256) atomicAdd(&h[d[e] >> BSH], 1);
    __syncthreads();
    if (tid < NBUCK) M[t * (NBUCK * NSB) + tid * NSB + k] = h[tid];
    return;
  }
  b -= 3 * NSB;
  int t = b * 256 + tid;
  const float* src;
  short* dst;
  int base;
  bool w1 = false;
  if (t < 16384) { src = W0_uu; dst = pW0_uu; base = t; }
  else if (t < 32768) { src = W0_ui; dst = pW0_ui; base = t - 16384; }
  else if (t < 49152) { src = W0_iu; dst = pW0_iu; base = t - 32768; }
  else if (t < 51200) { src = W1_uu; dst = pW1_uu; base = t - 49152; w1 = true; }
  else if (t < 53248) { src = W1_iu; dst = pW1_iu; base = t - 51200; w1 = true; }
  else return;
  int j = base & 7;
  int lane = (base >> 3) & 63;
  int frag = base >> 9;
  int quad = lane >> 4, l16 = lane & 15;
  float val;
  if (!w1) {
    int kc = frag >> 3, nt = frag & 7;
    val = src[(kc * 32 + quad * 8 + j) * 128 + nt * 16 + l16];
  } else {
    int kc = frag;
    val = src[(kc * 32 + quad * 8 + j) * 16 + l16];
  }
  dst[base] = bf16_bits(val);
}

// ---------------- 3-phase parallel scan over the 3 fine histograms ----------------
__global__ __launch_bounds__(1024) void scanA_kernel(int* __restrict__ off_uu,
                                                     int* __restrict__ off_iu,
                                                     int* __restrict__ off_ui,
                                                     int* __restrict__ partials) {
  int t = blockIdx.x / NCH, c = blockIdx.x % NCH;
  int* off = (t == 0) ? off_uu : (t == 1) ? off_iu : off_ui;
  const int n = NU + 1;
  __shared__ int wls[16];
  int tid = threadIdx.x, lane = tid & 63, wv = tid >> 6;
  int base = c * 4096 + tid * 4;
  int v0 = 0, v1 = 0, v2 = 0, v3 = 0;
  if (base + 3 < n) {
    v0 = off[base]; v1 = off[base + 1]; v2 = off[base + 2]; v3 = off[base + 3];
  } else {
    if (base < n) v0 = off[base];
    if (base + 1 < n) v1 = off[base + 1];
    if (base + 2 < n) v2 = off[base + 2];
  }
  int a0 = v0, a1 = a0 + v1, a2 = a1 + v2, a3 = a2 + v3;
  int s = a3, x = s;
#pragma unroll
  for (int d = 1; d < 64; d <<= 1) {
    int y = __shfl_up(x, d, 64);
    if (lane >= d) x += y;
  }
  if (lane == 63) wls[wv] = x;
  __syncthreads();
  if (wv == 0 && lane < 16) {
    int tt = wls[lane];
#pragma unroll
    for (int d = 1; d < 16; d <<= 1) {
      int y = __shfl_up(tt, d, 16);
      if ((lane & 15) >= d) tt += y;
    }
    wls[lane] = tt;
  }
  __syncthreads();
  int excl = x - s + (wv > 0 ? wls[wv - 1] : 0);
  if (base < n) off[base] = a0 + excl;
  if (base + 1 < n) off[base + 1] = a1 + excl;
  if (base + 2 < n) off[base + 2] = a2 + excl;
  if (base + 3 < n) off[base + 3] = a3 + excl;
  if (tid == 1023) partials[t * NCH + c] = wls[15];
}

__global__ void scanB_kernel(int* __restrict__ partials) {
  int wv = threadIdx.x >> 6, lane = threadIdx.x & 63;
  if (wv < 3 && lane < 32) {
    int x = (lane < NCH) ? partials[wv * NCH + lane] : 0;
#pragma unroll
    for (int d = 1; d < 32; d <<= 1) {
      int y = __shfl_up(x, d, 32);
      if ((lane & 31) >= d) x += y;
    }
    if (lane < NCH) partials[wv * NCH + lane] = x;
  }
}

__global__ __launch_bounds__(1024) void scanC_kernel(int* __restrict__ off_uu,
                                                     int* __restrict__ off_iu,
                                                     int* __restrict__ off_ui,
                                                     const int* __restrict__ partials) {
  int t = blockIdx.x / NCH, c = blockIdx.x % NCH;
  int* off = (t == 0) ? off_uu : (t == 1) ? off_iu : off_ui;
  int prefix = (c > 0) ? partials[t * NCH + c - 1] : 0;
  int base = c * 4096 + threadIdx.x * 4;
#pragma unroll
  for (int j = 0; j < 4; j++) {
    int i = base + j;
    if (i <= NU) off[i] += prefix;
  }
}

// ---------------- coarse-sort offsets: exclusive scan of M[b][:] + bucket base ----------------
__global__ __launch_bounds__(256) void scanM_kernel(int* __restrict__ M,
                                                    const int* __restrict__ off_uu,
                                                    const int* __restrict__ off_iu,
                                                    const int* __restrict__ off_ui) {
  int t = blockIdx.x / NBUCK, b = blockIdx.x % NBUCK;
  const int* off = (t == 0) ? off_uu : (t == 1) ? off_iu : off_ui;
  int* Mt = M + t * (NBUCK * NSB) + b * NSB;
  __shared__ int wls[4];
  int tid = threadIdx.x, lane = tid & 63, wv = tid >> 6;
  int v = Mt[tid];
  int x = v;
#pragma unroll
  for (int d = 1; d < 64; d <<= 1) {
    int y = __shfl_up(x, d, 64);
    if (lane >= d) x += y;
  }
  if (lane == 63) wls[wv] = x;
  __syncthreads();
  if (tid == 0) {
    int r = 0;
#pragma unroll
    for (int i = 0; i < 4; i++) { int tt = wls[i]; wls[i] = r; r += tt; }
  }
  __syncthreads();
  int boff = off[min(b << BSH, NU)];
  Mt[tid] = boff + x + wls[wv] - v;  // exclusive + bucket base
}

// ---------------- coarse scatter: block-private dense pair writes ----------------
__global__ __launch_bounds__(256) void coarse_scatter_kernel(
    const int* __restrict__ s_uu, const int* __restrict__ d_uu,
    const int* __restrict__ s_iu, const int* __restrict__ d_iu,
    const int* __restrict__ s_ui, const int* __restrict__ d_ui,
    const int* __restrict__ M, uint2* __restrict__ pairs) {
  __shared__ int cur[NBUCK];
  int t = blockIdx.x / NSB, k = blockIdx.x % NSB;
  int tid = threadIdx.x;
  if (tid < NBUCK) cur[tid] = M[t * (NBUCK * NSB) + tid * NSB + k];
  __syncthreads();
  const int* src = (t == 0) ? s_uu : (t == 1) ? s_iu : s_ui;
  const int* dst = (t == 0) ? d_uu : (t == 1) ? d_iu : d_ui;
  uint2* pr = pairs + (size_t)t * NEDGE;
  int e0 = k * SCH, e1 = min(e0 + SCH, NEDGE);
  for (int e = e0 + tid; e < e1; e += 256) {
    int d = dst[e];
    int pos = atomicAdd(&cur[d >> BSH], 1);
    pr[pos] = make_uint2((unsigned)src[e], (unsigned)d);
  }
}

// ---------------- fine CSR build: one block per bucket, LDS cursors ----------------
__global__ __launch_bounds__(256) void fine_sort_kernel(
    const uint2* __restrict__ pairs, const int* __restrict__ off_uu,
    const int* __restrict__ off_iu, const int* __restrict__ off_ui,
    int* __restrict__ ssrc_uu, int* __restrict__ ssrc_iu, int* __restrict__ ssrc_ui) {
  __shared__ int cur[1 << BSH];
  int t = blockIdx.x / NBUCK, b = blockIdx.x % NBUCK;
  int tid = threadIdx.x;
  const int* off = (t == 0) ? off_uu : (t == 1) ? off_iu : off_ui;
  int* ss = (t == 0) ? ssrc_uu : (t == 1) ? ssrc_iu : ssrc_ui;
  const uint2* pr = pairs + (size_t)t * NEDGE;
  int base = b << BSH;
  int nn = min(1 << BSH, NU - base);
  for (int i = tid; i < nn; i += 256) cur[i] = off[base + i];
  __syncthreads();
  int lo = off[base], hi = off[base + nn];
  for (int e = lo + tid; e < hi; e += 256) {
    uint2 p = pr[e];
    int pos = atomicAdd(&cur[(int)p.y - base], 1);
    ss[pos] = (int)p.x;
  }
}

// ---------------- segment mean (3 etypes): 4 nodes/wave, uint4 gathers ----------------
__global__ __launch_bounds__(256) void agg3_kernel(
    const unsigned* __restrict__ Xu, const void* __restrict__ Xi, int xi_bf16,
    const int* __restrict__ off_ui, const int* __restrict__ off_uu, const int* __restrict__ off_iu,
    const int* __restrict__ s_ui, const int* __restrict__ s_uu, const int* __restrict__ s_iu,
    uint4* __restrict__ A_ui, uint4* __restrict__ A_uu, uint4* __restrict__ A_iu, int nb1) {
  int seg = blockIdx.x / nb1;
  int node = (blockIdx.x % nb1) * 16 + (threadIdx.x >> 4);  // 16 lanes per node
  int l16 = threadIdx.x & 15;
  const int* off;
  const int* ss;
  uint4* A;
  if (seg == 0) { off = off_ui; ss = s_ui; A = A_ui; }
  else if (seg == 1) { off = off_uu; ss = s_uu; A = A_uu; }
  else { off = off_iu; ss = s_iu; A = A_iu; }
  if (node >= NPAD) return;
  float ac[8];
#pragma unroll
  for (int j = 0; j < 8; j++) ac[j] = 0.f;
  int deg = 0;
  if (node < NU) {
    int s0 = off[node], s1 = off[node + 1];
    deg = s1 - s0;
    if (seg < 2 || xi_bf16) {
      const uint4* X = (const uint4*)((seg < 2) ? Xu : (const unsigned*)Xi);
      int e = s0;
      for (; e + 4 <= s1; e += 4) {
        int ia = ss[e], ib = ss[e + 1], ic = ss[e + 2], id = ss[e + 3];
        uint4 va = X[(size_t)ia * 16 + l16];
        uint4 vb = X[(size_t)ib * 16 + l16];
        uint4 vc = X[(size_t)ic * 16 + l16];
        uint4 vd = X[(size_t)id * 16 + l16];
        bf2_acc(va.x, ac[0], ac[1]); bf2_acc(va.y, ac[2], ac[3]);
        bf2_acc(va.z, ac[4], ac[5]); bf2_acc(va.w, ac[6], ac[7]);
        bf2_acc(vb.x, ac[0], ac[1]); bf2_acc(vb.y, ac[2], ac[3]);
        bf2_acc(vb.z, ac[4], ac[5]); bf2_acc(vb.w, ac[6], ac[7]);
        bf2_acc(vc.x, ac[0], ac[1]); bf2_acc(vc.y, ac[2], ac[3]);
        bf2_acc(vc.z, ac[4], ac[5]); bf2_acc(vc.w, ac[6], ac[7]);
        bf2_acc(vd.x, ac[0], ac[1]); bf2_acc(vd.y, ac[2], ac[3]);
        bf2_acc(vd.z, ac[4], ac[5]); bf2_acc(vd.w, ac[6], ac[7]);
      }
      for (; e < s1; e++) {
        uint4 v = X[(size_t)ss[e] * 16 + l16];
        bf2_acc(v.x, ac[0], ac[1]); bf2_acc(v.y, ac[2], ac[3]);
        bf2_acc(v.z, ac[4], ac[5]); bf2_acc(v.w, ac[6], ac[7]);
      }
    } else {
      const float4* Xf = (const float4*)Xi;
      int e = s0;
      for (; e + 2 <= s1; e += 2) {
        int ia = ss[e], ib = ss[e + 1];
        float4 pa = Xf[(size_t)ia * 32 + l16 * 2];
        float4 qa = Xf[(size_t)ia * 32 + l16 * 2 + 1];
        float4 pb = Xf[(size_t)ib * 32 + l16 * 2];
        float4 qb = Xf[(size_t)ib * 32 + l16 * 2 + 1];
        ac[0] += pa.x + pb.x; ac[1] += pa.y + pb.y;
        ac[2] += pa.z + pb.z; ac[3] += pa.w + pb.w;
        ac[4] += qa.x + qb.x; ac[5] += qa.y + qb.y;
        ac[6] += qa.z + qb.z; ac[7] += qa.w + qb.w;
      }
      for (; e < s1; e++) {
        int ia = ss[e];
        float4 pa = Xf[(size_t)ia * 32 + l16 * 2];
        float4 qa = Xf[(size_t)ia * 32 + l16 * 2 + 1];
        ac[0] += pa.x; ac[1] += pa.y; ac[2] += pa.z; ac[3] += pa.w;
        ac[4] += qa.x; ac[5] += qa.y; ac[6] += qa.z; ac[7] += qa.w;
      }
    }
  }
  float inv = 1.0f / fmaxf((float)deg, 1.0f);
  uint4 o;
  o.x = pack_bf16(ac[0] * inv, ac[1] * inv);
  o.y = pack_bf16(ac[2] * inv, ac[3] * inv);
  o.z = pack_bf16(ac[4] * inv, ac[5] * inv);
  o.w = pack_bf16(ac[6] * inv, ac[7] * inv);
  A[(size_t)node * 16 + l16] = o;
}

// ---------------- fused MFMA rows ----------------
__global__ __launch_bounds__(256) void rows_mfma_kernel(
    const __hip_bfloat16* __restrict__ A_ui, const __hip_bfloat16* __restrict__ A_uu,
    const __hip_bfloat16* __restrict__ A_iu, const int* __restrict__ off_ui,
    const int* __restrict__ off_uu, const int* __restrict__ off_iu,
    const short* __restrict__ pW0_ui, const short* __restrict__ pW0_uu,
    const short* __restrict__ pW0_iu, const float* __restrict__ b0_ui,
    const float* __restrict__ b0_uu, const float* __restrict__ b0_iu,
    const short* __restrict__ pW1_iu, const short* __restrict__ pW1_uu,
    const float* __restrict__ b1_iu, const float* __restrict__ b1_uu,
    float* __restrict__ P_iu, float* __restrict__ P_uu, int nbi) {
  __shared__ float hs[4][2560];

  const int tid = threadIdx.x;
  const int w = tid >> 6, lane = tid & 63;
  const int quad = lane >> 4, l16 = lane & 15;
  const bool user = (int)blockIdx.x >= nbi;
  const int blk = user ? (int)blockIdx.x - nbi : (int)blockIdx.x;
  const int rb = blk * 64 + w * 16;

  const __hip_bfloat16* A0 = user ? A_uu : A_ui;
  const int* off0 = user ? off_uu : off_ui;
  const short* W0a = user ? pW0_uu : pW0_ui;
  const float* b0a = user ? b0_uu : b0_ui;
  const short* W1p = user ? pW1_uu : pW1_iu;
  const float* b1v = user ? b1_uu : b1_iu;
  float* P = user ? P_uu : P_iu;

  float m0[4], m1[4];
#pragma unroll
  for (int r = 0; r < 4; r++) {
    int rr = rb + quad * 4 + r;
    m0[r] = 0.f;
    m1[r] = 0.f;
    if (rr < NU) {
      m0[r] = (off0[rr + 1] > off0[rr]) ? 1.f : 0.f;
      if (user) m1[r] = (off_iu[rr + 1] > off_iu[rr]) ? 1.f : 0.f;
    }
  }

  f32x4 acc[8];
#pragma unroll
  for (int nt = 0; nt < 8; nt++) {
    float ba = b0a[nt * 16 + l16];
    float bb = user ? b0_iu[nt * 16 + l16] : 0.f;
#pragma unroll
    for (int r = 0; r < 4; r++) acc[nt][r] = ba * m0[r] + bb * m1[r];
  }

  const short8* A0v = (const short8*)(A0 + (size_t)(rb + l16) * DIN);
  const short8* A1v = (const short8*)(A_iu + (size_t)(rb + l16) * DIN);
  const short8* B0p = (const short8*)W0a;
  const short8* B1p = (const short8*)pW0_iu;

#pragma unroll
  for (int kc = 0; kc < 4; kc++) {
    short8 a0 = A0v[kc * 4 + quad];
    short8 a1 = user ? A1v[kc * 4 + quad] : a0;
#pragma unroll
    for (int nt = 0; nt < 8; nt++) {
      short8 b0 = B0p[(kc * 8 + nt) * 64 + lane];
      acc[nt] = __builtin_amdgcn_mfma_f32_16x16x32_bf16(a0, b0, acc[nt], 0, 0, 0);
      if (user) {
        short8 bb = B1p[(kc * 8 + nt) * 64 + lane];
        acc[nt] = __builtin_amdgcn_mfma_f32_16x16x32_bf16(a1, bb, acc[nt], 0, 0, 0);
      }
    }
  }

  float* hw = &hs[w][0];
#pragma unroll
  for (int nt = 0; nt < 8; nt++) {
    int col = nt * 16 + l16;
    float4 v;
    v.x = fmaxf(acc[nt][0], 0.f);
    v.y = fmaxf(acc[nt][1], 0.f);
    v.z = fmaxf(acc[nt][2], 0.f);
    v.w = fmaxf(acc[nt][3], 0.f);
    *(float4*)&hw[col * 20 + quad * 4] = v;
  }
  __syncthreads();

  f32x4 acc2;
  {
    float bv = b1v[l16];
    acc2[0] = bv; acc2[1] = bv; acc2[2] = bv; acc2[3] = bv;
  }
  const short8* W1f = (const short8*)W1p;
#pragma unroll
  for (int kc = 0; kc < 4; kc++) {
    float f[8];
#pragma unroll
    for (int j = 0; j < 8; j++) f[j] = hw[(kc * 32 + quad * 8 + j) * 20 + l16];
    union { uint4 u; short8 s; } hf;
    hf.u.x = pack_bf16(f[0], f[1]);
    hf.u.y = pack_bf16(f[2], f[3]);
    hf.u.z = pack_bf16(f[4], f[5]);
    hf.u.w = pack_bf16(f[6], f[7]);
    short8 bw = W1f[kc * 64 + lane];
    acc2 = __builtin_amdgcn_mfma_f32_16x16x32_bf16(hf.s, bw, acc2, 0, 0, 0);
  }
#pragma unroll
  for (int r = 0; r < 4; r++) {
    int rr = rb + quad * 4 + r;
    if (rr < NU) P[(size_t)rr * DOUT + l16] = acc2[r];
  }
}

// ---------------- fused output ----------------
__global__ __launch_bounds__(256) void out_kernel(const float* __restrict__ P_uu,
                                                  const float* __restrict__ P_iu,
                                                  const int* __restrict__ off_uu,
                                                  const int* __restrict__ s_uu,
                                                  const int* __restrict__ off_iu,
                                                  const int* __restrict__ s_iu,
                                                  float* __restrict__ out) {
  int node = blockIdx.x * 4 + (threadIdx.x >> 6);
  if (node >= NU) return;
  int lane = threadIdx.x & 63;
  int sub = lane >> 4, elem = lane & 15;
  float a = 0.f, b = 0.f;
  int s0 = off_uu[node], s1 = off_uu[node + 1];
  for (int e = s0 + sub; e < s1; e += 4) a += P_uu[(size_t)s_uu[e] * DOUT + elem];
  int t0 = off_iu[node], t1 = off_iu[node + 1];
  for (int e = t0 + sub; e < t1; e += 4) b += P_iu[(size_t)s_iu[e] * DOUT + elem];
  float r = a * (1.0f / fmaxf((float)(s1 - s0), 1.0f)) +
            b * (1.0f / fmaxf((float)(t1 - t0), 1.0f));
  r += __shfl_xor(r, 16, 64);
  r += __shfl_xor(r, 32, 64);
  if (lane < 16) out[(size_t)node * DOUT + elem] = r;
}

extern "C" void kernel_launch(void* const* d_in, const int* in_sizes, int n_in,
                              void* d_out, int out_size, void* d_ws, size_t ws_size,
                              hipStream_t stream) {
  (void)in_sizes; (void)n_in; (void)out_size;
  const float* embed_user = (const float*)d_in[0];
  const float* embed_item = (const float*)d_in[1];
  const int* src_uu = (const int*)d_in[2];
  const int* dst_uu = (const int*)d_in[3];
  const int* src_ui = (const int*)d_in[4];
  const int* dst_ui = (const int*)d_in[5];
  const int* src_iu = (const int*)d_in[6];
  const int* dst_iu = (const int*)d_in[7];
  const float* W0_uu = (const float*)d_in[8];
  const float* b0_uu = (const float*)d_in[9];
  const float* W0_ui = (const float*)d_in[10];
  const float* b0_ui = (const float*)d_in[11];
  const float* W0_iu = (const float*)d_in[12];
  const float* b0_iu = (const float*)d_in[13];
  const float* W1_uu = (const float*)d_in[14];
  const float* b1_uu = (const float*)d_in[15];
  const float* W1_iu = (const float*)d_in[18];
  const float* b1_iu = (const float*)d_in[19];
  float* out = (float*)d_out;

  char* ws = (char*)d_ws;
  unsigned* Eu_b = (unsigned*)(ws + W_EU * 4);
  unsigned* A_ui = (unsigned*)(ws + W_AUI * 4);
  unsigned* A_uu = (unsigned*)(ws + W_AUU * 4);
  unsigned* A_iu = (unsigned*)(ws + W_AIU * 4);
  short* pW0_uu = (short*)(ws + W_PW * 4);
  short* pW0_ui = pW0_uu + 16384;
  short* pW0_iu = pW0_uu + 32768;
  short* pW1_uu = pW0_uu + 49152;
  short* pW1_iu = pW0_uu + 51200;
  int* off_uu = (int*)(ws + W_OFFU * 4);
  int* off_iu = (int*)(ws + W_OFFI * 4);
  int* off_ui = (int*)(ws + W_OFFX * 4);
  int* ssrc_uu = (int*)(ws + W_SUU * 4);
  int* ssrc_iu = (int*)(ws + W_SIU * 4);
  int* ssrc_ui = (int*)(ws + W_SUI * 4);
  int* partials = (int*)(ws + W_PART * 4);
  unsigned* Ei_b = (unsigned*)(ws + W_EI * 4);
  uint2* pairs = (uint2*)A_ui;      // 3.6M w, dead before agg3 writes A_ui
  int* M = (int*)A_uu;              // 150,528 w, dead before agg3 writes A_uu
  float* P_iu = (float*)Eu_b;       // Eu_b dead after agg3
  float* P_uu = P_iu + 1600000;

  const int full = (ws_size >= WS_FULL_BYTES) ? 1 : 0;
  const int nconvU = 6250, nconvI = full ? 6250 : 0;
  const void* Xi = full ? (const void*)Ei_b : (const void*)embed_item;

  hipMemsetAsync(off_uu, 0, 300048ull * 4, stream);

  prep_kernel<<<nconvU + nconvI + 3 * 2344 + 3 * NSB + 208, 256, 0, stream>>>(
      embed_user, embed_item, Eu_b, Ei_b, dst_uu, dst_iu, dst_ui, off_uu, off_iu, off_ui,
      M, W0_uu, W0_ui, W0_iu, W1_uu, W1_iu, pW0_uu, pW0_ui, pW0_iu, pW1_uu, pW1_iu,
      nconvU, nconvI);

  scanA_kernel<<<3 * NCH, 1024, 0, stream>>>(off_uu, off_iu, off_ui, partials);
  scanB_kernel<<<1, 256, 0, stream>>>(partials);
  scanC_kernel<<<3 * NCH, 1024, 0, stream>>>(off_uu, off_iu, off_ui, partials);

  scanM_kernel<<<3 * NBUCK, 256, 0, stream>>>(M, off_uu, off_iu, off_ui);
  coarse_scatter_kernel<<<3 * NSB, 256, 0, stream>>>(src_uu, dst_uu, src_iu, dst_iu,
                                                     src_ui, dst_ui, M, pairs);
  fine_sort_kernel<<<3 * NBUCK, 256, 0, stream>>>(pairs, off_uu, off_iu, off_ui,
                                                  ssrc_uu, ssrc_iu, ssrc_ui);

  const int nb1 = NPAD / 16;  // 6252 blocks per etype, 16 nodes per block
  agg3_kernel<<<3 * nb1, 256, 0, stream>>>(Eu_b, Xi, full, off_ui, off_uu, off_iu,
                                           ssrc_ui, ssrc_uu, ssrc_iu,
                                           (uint4*)A_ui, (uint4*)A_uu, (uint4*)A_iu, nb1);

  const int nbi = NPAD / 64;
  rows_mfma_kernel<<<2 * nbi, 256, 0, stream>>>(
      (const __hip_bfloat16*)A_ui, (const __hip_bfloat16*)A_uu, (const __hip_bfloat16*)A_iu,
      off_ui, off_uu, off_iu, pW0_ui, pW0_uu, pW0_iu, b0_ui, b0_uu, b0_iu,
      pW1_iu, pW1_uu, b1_iu, b1_uu, P_iu, P_uu, nbi);

  out_kernel<<<(NU + 3) / 4, 256, 0, stream>>>(P_uu, P_iu, off_uu, ssrc_uu, off_iu, ssrc_iu, out);
}

// Round 6
// 401.447 us; speedup vs baseline: 2.3441x; 1.1644x over previous
//
#include <hip/hip_runtime.h>
#include <hip/hip_bf16.h>

#define NU 100000
#define NI 100000
#define NEDGE 600000
#define DIN 128
#define DOUT 16
#define NPAD 100032   // 1563 * 64; also 6252 * 16
#define BSH 9         // coarse bucket shift
#define NBUCK 196     // ceil(100000 / 512)
#define NSB 256       // coarse-sort blocks per etype
#define SCH 2344      // edges per coarse-sort block (256*2344 >= 600000)

typedef __attribute__((ext_vector_type(8))) short short8;
typedef __attribute__((ext_vector_type(4))) float f32x4;

// ---- workspace word offsets ----
#define W_EU   0ull          // 6,400,000 w bf16 user table; P_iu@0, P_uu@1.6M alias after agg
#define W_AUI  6400000ull    // 6,402,048 w each A buffer; pairs alias A_ui pre-agg
#define W_AUU  12802048ull   // M/Btot/Bbase alias A_uu head pre-agg
#define W_AIU  19204096ull
#define W_PW   25606144ull   // packed weights, 26,624 w
#define W_OFFU 25632768ull   // 100,016 w each
#define W_OFFI 25732784ull
#define W_OFFX 25832800ull
#define W_SUU  25932816ull   // 600,000 w each
#define W_SIU  26532816ull
#define W_SUI  27132816ull
#define W_EI   27732944ull   // 6,400,000 w (optional)
#define WS_FULL_BYTES (34132944ull * 4)

__device__ inline unsigned pack_bf16(float x, float y) {
  __hip_bfloat162 h = __float22bfloat162_rn(make_float2(x, y));
  unsigned u;
  __builtin_memcpy(&u, &h, 4);
  return u;
}

__device__ inline short bf16_bits(float x) {
  __hip_bfloat16 h = __float2bfloat16(x);
  short s;
  __builtin_memcpy(&s, &h, 2);
  return s;
}

__device__ inline void bf2_acc(unsigned u, float& ax, float& ay) {
  unsigned lo = u << 16, hi = u & 0xffff0000u;
  float f0, f1;
  __builtin_memcpy(&f0, &lo, 4);
  __builtin_memcpy(&f1, &hi, 4);
  ax += f0;
  ay += f1;
}

// ---------------- prep: embed->bf16 + coarse LDS counts + weight repack (NO global atomics) ----
__global__ __launch_bounds__(256) void prep_kernel(
    const float* __restrict__ Eu, const float* __restrict__ Ei,
    unsigned* __restrict__ Eu_b, unsigned* __restrict__ Ei_b,
    const int* __restrict__ d_uu, const int* __restrict__ d_iu, const int* __restrict__ d_ui,
    int* __restrict__ M,
    const float* __restrict__ W0_uu, const float* __restrict__ W0_ui,
    const float* __restrict__ W0_iu, const float* __restrict__ W1_uu,
    const float* __restrict__ W1_iu, short* __restrict__ pW0_uu, short* __restrict__ pW0_ui,
    short* __restrict__ pW0_iu, short* __restrict__ pW1_uu, short* __restrict__ pW1_iu,
    int nconvU, int nconvI) {
  __shared__ int h[NBUCK];
  int b = blockIdx.x;
  int tid = threadIdx.x;
  if (b < nconvU + nconvI) {
    const float* src;
    unsigned* dst;
    int t;
    if (b < nconvU) { src = Eu; dst = Eu_b; t = b * 256 + tid; }
    else { src = Ei; dst = Ei_b; t = (b - nconvU) * 256 + tid; }
    const float4* s4 = (const float4*)src;
    float4 x = s4[(size_t)t * 2], y = s4[(size_t)t * 2 + 1];
    uint4 o;
    o.x = pack_bf16(x.x, x.y);
    o.y = pack_bf16(x.z, x.w);
    o.z = pack_bf16(y.x, y.y);
    o.w = pack_bf16(y.z, y.w);
    ((uint4*)dst)[t] = o;
    return;
  }
  b -= nconvU + nconvI;
  if (b < 3 * NSB) {
    int t = b / NSB, k = b % NSB;
    if (tid < NBUCK) h[tid] = 0;
    __syncthreads();
    const int* d = (t == 0) ? d_uu : (t == 1) ? d_iu : d_ui;
    int e0 = k * SCH, e1 = min(e0 + SCH, NEDGE);
    for (int e = e0 + tid; e < e1; e += 256) atomicAdd(&h[d[e] >> BSH], 1);
    __syncthreads();
    if (tid < NBUCK) M[t * (NBUCK * NSB) + tid * NSB + k] = h[tid];
    return;
  }
  b -= 3 * NSB;
  int t = b * 256 + tid;
  const float* src;
  short* dst;
  int base;
  bool w1 = false;
  if (t < 16384) { src = W0_uu; dst = pW0_uu; base = t; }
  else if (t < 32768) { src = W0_ui; dst = pW0_ui; base = t - 16384; }
  else if (t < 49152) { src = W0_iu; dst = pW0_iu; base = t - 32768; }
  else if (t < 51200) { src = W1_uu; dst = pW1_uu; base = t - 49152; w1 = true; }
  else if (t < 53248) { src = W1_iu; dst = pW1_iu; base = t - 51200; w1 = true; }
  else return;
  int j = base & 7;
  int lane = (base >> 3) & 63;
  int frag = base >> 9;
  int quad = lane >> 4, l16 = lane & 15;
  float val;
  if (!w1) {
    int kc = frag >> 3, nt = frag & 7;
    val = src[(kc * 32 + quad * 8 + j) * 128 + nt * 16 + l16];
  } else {
    int kc = frag;
    val = src[(kc * 32 + quad * 8 + j) * 16 + l16];
  }
  dst[base] = bf16_bits(val);
}

// ---------------- scanM: per-(bucket) local exclusive offsets across blocks + bucket totals ----
__global__ __launch_bounds__(256) void scanM_kernel(int* __restrict__ M,
                                                    int* __restrict__ Btot) {
  int t = blockIdx.x / NBUCK, b = blockIdx.x % NBUCK;
  int* Mt = M + t * (NBUCK * NSB) + b * NSB;
  __shared__ int wls[4];
  __shared__ int tot;
  int tid = threadIdx.x, lane = tid & 63, wv = tid >> 6;
  int v = Mt[tid];
  int x = v;
#pragma unroll
  for (int d = 1; d < 64; d <<= 1) {
    int y = __shfl_up(x, d, 64);
    if (lane >= d) x += y;
  }
  if (lane == 63) wls[wv] = x;
  __syncthreads();
  if (tid == 0) {
    int r = 0;
#pragma unroll
    for (int i = 0; i < 4; i++) { int tt = wls[i]; wls[i] = r; r += tt; }
    tot = r;
  }
  __syncthreads();
  Mt[tid] = x - v + wls[wv];  // local exclusive offset within bucket
  if (tid == 0) Btot[t * NBUCK + b] = tot;
}

// ---------------- scanB: exclusive scan of bucket totals -> global bucket bases ----------------
__global__ __launch_bounds__(256) void scanB_kernel(const int* __restrict__ Btot,
                                                    int* __restrict__ Bbase) {
  int t = blockIdx.x;
  __shared__ int wls[4];
  int tid = threadIdx.x, lane = tid & 63, wv = tid >> 6;
  int v = (tid < NBUCK) ? Btot[t * NBUCK + tid] : 0;
  int x = v;
#pragma unroll
  for (int d = 1; d < 64; d <<= 1) {
    int y = __shfl_up(x, d, 64);
    if (lane >= d) x += y;
  }
  if (lane == 63) wls[wv] = x;
  __syncthreads();
  if (tid == 0) {
    int r = 0;
#pragma unroll
    for (int i = 0; i < 4; i++) { int tt = wls[i]; wls[i] = r; r += tt; }
  }
  __syncthreads();
  if (tid < NBUCK) Bbase[t * NBUCK + tid] = x - v + wls[wv];
}

// ---------------- coarse scatter: block-private dense pair writes ----------------
__global__ __launch_bounds__(256) void coarse_scatter_kernel(
    const int* __restrict__ s_uu, const int* __restrict__ d_uu,
    const int* __restrict__ s_iu, const int* __restrict__ d_iu,
    const int* __restrict__ s_ui, const int* __restrict__ d_ui,
    const int* __restrict__ M, const int* __restrict__ Bbase, uint2* __restrict__ pairs) {
  __shared__ int cur[NBUCK];
  int t = blockIdx.x / NSB, k = blockIdx.x % NSB;
  int tid = threadIdx.x;
  if (tid < NBUCK) cur[tid] = M[t * (NBUCK * NSB) + tid * NSB + k] + Bbase[t * NBUCK + tid];
  __syncthreads();
  const int* src = (t == 0) ? s_uu : (t == 1) ? s_iu : s_ui;
  const int* dst = (t == 0) ? d_uu : (t == 1) ? d_iu : d_ui;
  uint2* pr = pairs + (size_t)t * NEDGE;
  int e0 = k * SCH, e1 = min(e0 + SCH, NEDGE);
  for (int e = e0 + tid; e < e1; e += 256) {
    int d = dst[e];
    int pos = atomicAdd(&cur[d >> BSH], 1);
    pr[pos] = make_uint2((unsigned)src[e], (unsigned)d);
  }
}

// ---------------- fine sort: LDS hist + LDS scan -> off[] write + ssrc scatter ----------------
__global__ __launch_bounds__(256) void fine_sort_kernel(
    const uint2* __restrict__ pairs, const int* __restrict__ Bbase,
    const int* __restrict__ Btot,
    int* __restrict__ off_uu, int* __restrict__ off_iu, int* __restrict__ off_ui,
    int* __restrict__ ssrc_uu, int* __restrict__ ssrc_iu, int* __restrict__ ssrc_ui) {
  __shared__ int h[1 << BSH];
  __shared__ int wls[4];
  int t = blockIdx.x / NBUCK, b = blockIdx.x % NBUCK;
  int tid = threadIdx.x, lane = tid & 63, wv = tid >> 6;
  int* off = (t == 0) ? off_uu : (t == 1) ? off_iu : off_ui;
  int* ss = (t == 0) ? ssrc_uu : (t == 1) ? ssrc_iu : ssrc_ui;
  const uint2* pr = pairs + (size_t)t * NEDGE;
  int base = b << BSH;
  int base_off = Bbase[t * NBUCK + b];
  int cnt = Btot[t * NBUCK + b];
  h[tid] = 0;
  h[tid + 256] = 0;
  __syncthreads();
  for (int e = base_off + tid; e < base_off + cnt; e += 256)
    atomicAdd(&h[(int)pr[e].y - base], 1);
  __syncthreads();
  // exclusive scan of 512 counters: thread i owns h[2i], h[2i+1]
  int h0 = h[2 * tid], h1 = h[2 * tid + 1];
  int s = h0 + h1, x = s;
#pragma unroll
  for (int d = 1; d < 64; d <<= 1) {
    int y = __shfl_up(x, d, 64);
    if (lane >= d) x += y;
  }
  if (lane == 63) wls[wv] = x;
  __syncthreads();
  if (tid == 0) {
    int r = 0;
#pragma unroll
    for (int i = 0; i < 4; i++) { int tt = wls[i]; wls[i] = r; r += tt; }
  }
  __syncthreads();
  int excl = base_off + x - s + wls[wv];
  h[2 * tid] = excl;
  h[2 * tid + 1] = excl + h0;
  __syncthreads();
  int nn = min(1 << BSH, NU - base);
  for (int i = tid; i < nn; i += 256) off[base + i] = h[i];
  if (b == NBUCK - 1 && tid == 0) off[NU] = base_off + cnt;  // = NEDGE
  __syncthreads();
  for (int e = base_off + tid; e < base_off + cnt; e += 256) {
    uint2 p = pr[e];
    int pos = atomicAdd(&h[(int)p.y - base], 1);
    ss[pos] = (int)p.x;
  }
}

// ---------------- segment mean (3 etypes): 4 nodes/wave, uint4 gathers ----------------
__global__ __launch_bounds__(256) void agg3_kernel(
    const unsigned* __restrict__ Xu, const void* __restrict__ Xi, int xi_bf16,
    const int* __restrict__ off_ui, const int* __restrict__ off_uu, const int* __restrict__ off_iu,
    const int* __restrict__ s_ui, const int* __restrict__ s_uu, const int* __restrict__ s_iu,
    uint4* __restrict__ A_ui, uint4* __restrict__ A_uu, uint4* __restrict__ A_iu, int nb1) {
  int seg = blockIdx.x / nb1;
  int node = (blockIdx.x % nb1) * 16 + (threadIdx.x >> 4);
  int l16 = threadIdx.x & 15;
  const int* off;
  const int* ss;
  uint4* A;
  if (seg == 0) { off = off_ui; ss = s_ui; A = A_ui; }
  else if (seg == 1) { off = off_uu; ss = s_uu; A = A_uu; }
  else { off = off_iu; ss = s_iu; A = A_iu; }
  if (node >= NPAD) return;
  float ac[8];
#pragma unroll
  for (int j = 0; j < 8; j++) ac[j] = 0.f;
  int deg = 0;
  if (node < NU) {
    int s0 = off[node], s1 = off[node + 1];
    deg = s1 - s0;
    if (seg < 2 || xi_bf16) {
      const uint4* X = (const uint4*)((seg < 2) ? Xu : (const unsigned*)Xi);
      int e = s0;
      for (; e + 4 <= s1; e += 4) {
        int ia = ss[e], ib = ss[e + 1], ic = ss[e + 2], id = ss[e + 3];
        uint4 va = X[(size_t)ia * 16 + l16];
        uint4 vb = X[(size_t)ib * 16 + l16];
        uint4 vc = X[(size_t)ic * 16 + l16];
        uint4 vd = X[(size_t)id * 16 + l16];
        bf2_acc(va.x, ac[0], ac[1]); bf2_acc(va.y, ac[2], ac[3]);
        bf2_acc(va.z, ac[4], ac[5]); bf2_acc(va.w, ac[6], ac[7]);
        bf2_acc(vb.x, ac[0], ac[1]); bf2_acc(vb.y, ac[2], ac[3]);
        bf2_acc(vb.z, ac[4], ac[5]); bf2_acc(vb.w, ac[6], ac[7]);
        bf2_acc(vc.x, ac[0], ac[1]); bf2_acc(vc.y, ac[2], ac[3]);
        bf2_acc(vc.z, ac[4], ac[5]); bf2_acc(vc.w, ac[6], ac[7]);
        bf2_acc(vd.x, ac[0], ac[1]); bf2_acc(vd.y, ac[2], ac[3]);
        bf2_acc(vd.z, ac[4], ac[5]); bf2_acc(vd.w, ac[6], ac[7]);
      }
      for (; e < s1; e++) {
        uint4 v = X[(size_t)ss[e] * 16 + l16];
        bf2_acc(v.x, ac[0], ac[1]); bf2_acc(v.y, ac[2], ac[3]);
        bf2_acc(v.z, ac[4], ac[5]); bf2_acc(v.w, ac[6], ac[7]);
      }
    } else {
      const float4* Xf = (const float4*)Xi;
      int e = s0;
      for (; e + 2 <= s1; e += 2) {
        int ia = ss[e], ib = ss[e + 1];
        float4 pa = Xf[(size_t)ia * 32 + l16 * 2];
        float4 qa = Xf[(size_t)ia * 32 + l16 * 2 + 1];
        float4 pb = Xf[(size_t)ib * 32 + l16 * 2];
        float4 qb = Xf[(size_t)ib * 32 + l16 * 2 + 1];
        ac[0] += pa.x + pb.x; ac[1] += pa.y + pb.y;
        ac[2] += pa.z + pb.z; ac[3] += pa.w + pb.w;
        ac[4] += qa.x + qb.x; ac[5] += qa.y + qb.y;
        ac[6] += qa.z + qb.z; ac[7] += qa.w + qb.w;
      }
      for (; e < s1; e++) {
        int ia = ss[e];
        float4 pa = Xf[(size_t)ia * 32 + l16 * 2];
        float4 qa = Xf[(size_t)ia * 32 + l16 * 2 + 1];
        ac[0] += pa.x; ac[1] += pa.y; ac[2] += pa.z; ac[3] += pa.w;
        ac[4] += qa.x; ac[5] += qa.y; ac[6] += qa.z; ac[7] += qa.w;
      }
    }
  }
  float inv = 1.0f / fmaxf((float)deg, 1.0f);
  uint4 o;
  o.x = pack_bf16(ac[0] * inv, ac[1] * inv);
  o.y = pack_bf16(ac[2] * inv, ac[3] * inv);
  o.z = pack_bf16(ac[4] * inv, ac[5] * inv);
  o.w = pack_bf16(ac[6] * inv, ac[7] * inv);
  A[(size_t)node * 16 + l16] = o;
}

// ---------------- fused MFMA rows ----------------
__global__ __launch_bounds__(256) void rows_mfma_kernel(
    const __hip_bfloat16* __restrict__ A_ui, const __hip_bfloat16* __restrict__ A_uu,
    const __hip_bfloat16* __restrict__ A_iu, const int* __restrict__ off_ui,
    const int* __restrict__ off_uu, const int* __restrict__ off_iu,
    const short* __restrict__ pW0_ui, const short* __restrict__ pW0_uu,
    const short* __restrict__ pW0_iu, const float* __restrict__ b0_ui,
    const float* __restrict__ b0_uu, const float* __restrict__ b0_iu,
    const short* __restrict__ pW1_iu, const short* __restrict__ pW1_uu,
    const float* __restrict__ b1_iu, const float* __restrict__ b1_uu,
    float* __restrict__ P_iu, float* __restrict__ P_uu, int nbi) {
  __shared__ float hs[4][2560];

  const int tid = threadIdx.x;
  const int w = tid >> 6, lane = tid & 63;
  const int quad = lane >> 4, l16 = lane & 15;
  const bool user = (int)blockIdx.x >= nbi;
  const int blk = user ? (int)blockIdx.x - nbi : (int)blockIdx.x;
  const int rb = blk * 64 + w * 16;

  const __hip_bfloat16* A0 = user ? A_uu : A_ui;
  const int* off0 = user ? off_uu : off_ui;
  const short* W0a = user ? pW0_uu : pW0_ui;
  const float* b0a = user ? b0_uu : b0_ui;
  const short* W1p = user ? pW1_uu : pW1_iu;
  const float* b1v = user ? b1_uu : b1_iu;
  float* P = user ? P_uu : P_iu;

  float m0[4], m1[4];
#pragma unroll
  for (int r = 0; r < 4; r++) {
    int rr = rb + quad * 4 + r;
    m0[r] = 0.f;
    m1[r] = 0.f;
    if (rr < NU) {
      m0[r] = (off0[rr + 1] > off0[rr]) ? 1.f : 0.f;
      if (user) m1[r] = (off_iu[rr + 1] > off_iu[rr]) ? 1.f : 0.f;
    }
  }

  f32x4 acc[8];
#pragma unroll
  for (int nt = 0; nt < 8; nt++) {
    float ba = b0a[nt * 16 + l16];
    float bb = user ? b0_iu[nt * 16 + l16] : 0.f;
#pragma unroll
    for (int r = 0; r < 4; r++) acc[nt][r] = ba * m0[r] + bb * m1[r];
  }

  const short8* A0v = (const short8*)(A0 + (size_t)(rb + l16) * DIN);
  const short8* A1v = (const short8*)(A_iu + (size_t)(rb + l16) * DIN);
  const short8* B0p = (const short8*)W0a;
  const short8* B1p = (const short8*)pW0_iu;

#pragma unroll
  for (int kc = 0; kc < 4; kc++) {
    short8 a0 = A0v[kc * 4 + quad];
    short8 a1 = user ? A1v[kc * 4 + quad] : a0;
#pragma unroll
    for (int nt = 0; nt < 8; nt++) {
      short8 b0 = B0p[(kc * 8 + nt) * 64 + lane];
      acc[nt] = __builtin_amdgcn_mfma_f32_16x16x32_bf16(a0, b0, acc[nt], 0, 0, 0);
      if (user) {
        short8 bb = B1p[(kc * 8 + nt) * 64 + lane];
        acc[nt] = __builtin_amdgcn_mfma_f32_16x16x32_bf16(a1, bb, acc[nt], 0, 0, 0);
      }
    }
  }

  float* hw = &hs[w][0];
#pragma unroll
  for (int nt = 0; nt < 8; nt++) {
    int col = nt * 16 + l16;
    float4 v;
    v.x = fmaxf(acc[nt][0], 0.f);
    v.y = fmaxf(acc[nt][1], 0.f);
    v.z = fmaxf(acc[nt][2], 0.f);
    v.w = fmaxf(acc[nt][3], 0.f);
    *(float4*)&hw[col * 20 + quad * 4] = v;
  }
  __syncthreads();

  f32x4 acc2;
  {
    float bv = b1v[l16];
    acc2[0] = bv; acc2[1] = bv; acc2[2] = bv; acc2[3] = bv;
  }
  const short8* W1f = (const short8*)W1p;
#pragma unroll
  for (int kc = 0; kc < 4; kc++) {
    float f[8];
#pragma unroll
    for (int j = 0; j < 8; j++) f[j] = hw[(kc * 32 + quad * 8 + j) * 20 + l16];
    union { uint4 u; short8 s; } hf;
    hf.u.x = pack_bf16(f[0], f[1]);
    hf.u.y = pack_bf16(f[2], f[3]);
    hf.u.z = pack_bf16(f[4], f[5]);
    hf.u.w = pack_bf16(f[6], f[7]);
    short8 bw = W1f[kc * 64 + lane];
    acc2 = __builtin_amdgcn_mfma_f32_16x16x32_bf16(hf.s, bw, acc2, 0, 0, 0);
  }
#pragma unroll
  for (int r = 0; r < 4; r++) {
    int rr = rb + quad * 4 + r;
    if (rr < NU) P[(size_t)rr * DOUT + l16] = acc2[r];
  }
}

// ---------------- fused output ----------------
__global__ __launch_bounds__(256) void out_kernel(const float* __restrict__ P_uu,
                                                  const float* __restrict__ P_iu,
                                                  const int* __restrict__ off_uu,
                                                  const int* __restrict__ s_uu,
                                                  const int* __restrict__ off_iu,
                                                  const int* __restrict__ s_iu,
                                                  float* __restrict__ out) {
  int node = blockIdx.x * 4 + (threadIdx.x >> 6);
  if (node >= NU) return;
  int lane = threadIdx.x & 63;
  int sub = lane >> 4, elem = lane & 15;
  float a = 0.f, b = 0.f;
  int s0 = off_uu[node], s1 = off_uu[node + 1];
  for (int e = s0 + sub; e < s1; e += 4) a += P_uu[(size_t)s_uu[e] * DOUT + elem];
  int t0 = off_iu[node], t1 = off_iu[node + 1];
  for (int e = t0 + sub; e < t1; e += 4) b += P_iu[(size_t)s_iu[e] * DOUT + elem];
  float r = a * (1.0f / fmaxf((float)(s1 - s0), 1.0f)) +
            b * (1.0f / fmaxf((float)(t1 - t0), 1.0f));
  r += __shfl_xor(r, 16, 64);
  r += __shfl_xor(r, 32, 64);
  if (lane < 16) out[(size_t)node * DOUT + elem] = r;
}

extern "C" void kernel_launch(void* const* d_in, const int* in_sizes, int n_in,
                              void* d_out, int out_size, void* d_ws, size_t ws_size,
                              hipStream_t stream) {
  (void)in_sizes; (void)n_in; (void)out_size;
  const float* embed_user = (const float*)d_in[0];
  const float* embed_item = (const float*)d_in[1];
  const int* src_uu = (const int*)d_in[2];
  const int* dst_uu = (const int*)d_in[3];
  const int* src_ui = (const int*)d_in[4];
  const int* dst_ui = (const int*)d_in[5];
  const int* src_iu = (const int*)d_in[6];
  const int* dst_iu = (const int*)d_in[7];
  const float* W0_uu = (const float*)d_in[8];
  const float* b0_uu = (const float*)d_in[9];
  const float* W0_ui = (const float*)d_in[10];
  const float* b0_ui = (const float*)d_in[11];
  const float* W0_iu = (const float*)d_in[12];
  const float* b0_iu = (const float*)d_in[13];
  const float* W1_uu = (const float*)d_in[14];
  const float* b1_uu = (const float*)d_in[15];
  const float* W1_iu = (const float*)d_in[18];
  const float* b1_iu = (const float*)d_in[19];
  float* out = (float*)d_out;

  char* ws = (char*)d_ws;
  unsigned* Eu_b = (unsigned*)(ws + W_EU * 4);
  unsigned* A_ui = (unsigned*)(ws + W_AUI * 4);
  unsigned* A_uu = (unsigned*)(ws + W_AUU * 4);
  unsigned* A_iu = (unsigned*)(ws + W_AIU * 4);
  short* pW0_uu = (short*)(ws + W_PW * 4);
  short* pW0_ui = pW0_uu + 16384;
  short* pW0_iu = pW0_uu + 32768;
  short* pW1_uu = pW0_uu + 49152;
  short* pW1_iu = pW0_uu + 51200;
  int* off_uu = (int*)(ws + W_OFFU * 4);
  int* off_iu = (int*)(ws + W_OFFI * 4);
  int* off_ui = (int*)(ws + W_OFFX * 4);
  int* ssrc_uu = (int*)(ws + W_SUU * 4);
  int* ssrc_iu = (int*)(ws + W_SIU * 4);
  int* ssrc_ui = (int*)(ws + W_SUI * 4);
  unsigned* Ei_b = (unsigned*)(ws + W_EI * 4);
  uint2* pairs = (uint2*)A_ui;           // 3.6M w, dead before agg3 writes A_ui
  int* M = (int*)A_uu;                   // 150,528 w, dead before agg3 writes A_uu
  int* Btot = M + NBUCK * NSB * 3;       // 588 w
  int* Bbase = Btot + NBUCK * 3;         // 588 w (still within A_uu region)
  float* P_iu = (float*)Eu_b;            // Eu_b dead after agg3
  float* P_uu = P_iu + 1600000;

  const int full = (ws_size >= WS_FULL_BYTES) ? 1 : 0;
  const int nconvU = 6250, nconvI = full ? 6250 : 0;
  const void* Xi = full ? (const void*)Ei_b : (const void*)embed_item;

  prep_kernel<<<nconvU + nconvI + 3 * NSB + 208, 256, 0, stream>>>(
      embed_user, embed_item, Eu_b, Ei_b, dst_uu, dst_iu, dst_ui, M,
      W0_uu, W0_ui, W0_iu, W1_uu, W1_iu, pW0_uu, pW0_ui, pW0_iu, pW1_uu, pW1_iu,
      nconvU, nconvI);

  scanM_kernel<<<3 * NBUCK, 256, 0, stream>>>(M, Btot);
  scanB_kernel<<<3, 256, 0, stream>>>(Btot, Bbase);
  coarse_scatter_kernel<<<3 * NSB, 256, 0, stream>>>(src_uu, dst_uu, src_iu, dst_iu,
                                                     src_ui, dst_ui, M, Bbase, pairs);
  fine_sort_kernel<<<3 * NBUCK, 256, 0, stream>>>(pairs, Bbase, Btot,
                                                  off_uu, off_iu, off_ui,
                                                  ssrc_uu, ssrc_iu, ssrc_ui);

  const int nb1 = NPAD / 16;
  agg3_kernel<<<3 * nb1, 256, 0, stream>>>(Eu_b, Xi, full, off_ui, off_uu, off_iu,
                                           ssrc_ui, ssrc_uu, ssrc_iu,
                                           (uint4*)A_ui, (uint4*)A_uu, (uint4*)A_iu, nb1);

  const int nbi = NPAD / 64;
  rows_mfma_kernel<<<2 * nbi, 256, 0, stream>>>(
      (const __hip_bfloat16*)A_ui, (const __hip_bfloat16*)A_uu, (const __hip_bfloat16*)A_iu,
      off_ui, off_uu, off_iu, pW0_ui, pW0_uu, pW0_iu, b0_ui, b0_uu, b0_iu,
      pW1_iu, pW1_uu, b1_iu, b1_uu, P_iu, P_uu, nbi);

  out_kernel<<<(NU + 3) / 4, 256, 0, stream>>>(P_uu, P_iu, off_uu, ssrc_uu, off_iu, ssrc_iu, out);
}

// Round 8
// 373.632 us; speedup vs baseline: 2.5186x; 1.0744x over previous
//
#include <hip/hip_runtime.h>
#include <hip/hip_bf16.h>

#define NU 100000
#define NI 100000
#define NEDGE 600000
#define DIN 128
#define DOUT 16
#define NPAD 100032   // 1563 * 64; also 6252 * 16
#define BSH 9         // coarse bucket shift
#define NBUCK 196     // ceil(100000 / 512)
#define NSB 256       // coarse-sort blocks per etype
#define SCH 2344      // edges per coarse-sort block (256*2344 >= 600000)

typedef __attribute__((ext_vector_type(8))) short short8;
typedef __attribute__((ext_vector_type(4))) float f32x4;

// ---- workspace word offsets ----
#define W_EU   0ull          // 6,400,000 w bf16 user table; P_iu@0, P_uu@1.6M alias after agg
#define W_AUI  6400000ull    // 6,402,048 w each A buffer; pairs alias A_ui pre-agg
#define W_AUU  12802048ull   // M/Btot/Bbase alias A_uu head pre-agg
#define W_AIU  19204096ull
#define W_PW   25606144ull   // packed weights, 26,624 w
#define W_OFFU 25632768ull   // 100,016 w each
#define W_OFFI 25732784ull
#define W_OFFX 25832800ull
#define W_SUU  25932816ull   // 600,000 w each
#define W_SIU  26532816ull
#define W_SUI  27132816ull
#define W_EI   27732944ull   // 6,400,000 w (optional)
#define WS_FULL_BYTES (34132944ull * 4)

__device__ inline unsigned pack_bf16(float x, float y) {
  __hip_bfloat162 h = __float22bfloat162_rn(make_float2(x, y));
  unsigned u;
  __builtin_memcpy(&u, &h, 4);
  return u;
}

__device__ inline short bf16_bits(float x) {
  __hip_bfloat16 h = __float2bfloat16(x);
  short s;
  __builtin_memcpy(&s, &h, 2);
  return s;
}

__device__ inline void bf2_accw(unsigned u, float w, float& ax, float& ay) {
  unsigned lo = u << 16, hi = u & 0xffff0000u;
  float f0, f1;
  __builtin_memcpy(&f0, &lo, 4);
  __builtin_memcpy(&f1, &hi, 4);
  ax = fmaf(f0, w, ax);
  ay = fmaf(f1, w, ay);
}

// ---------------- prep: embed->bf16 + coarse LDS counts + weight repack (NO global atomics) ----
__global__ __launch_bounds__(256) void prep_kernel(
    const float* __restrict__ Eu, const float* __restrict__ Ei,
    unsigned* __restrict__ Eu_b, unsigned* __restrict__ Ei_b,
    const int* __restrict__ d_uu, const int* __restrict__ d_iu, const int* __restrict__ d_ui,
    int* __restrict__ M,
    const float* __restrict__ W0_uu, const float* __restrict__ W0_ui,
    const float* __restrict__ W0_iu, const float* __restrict__ W1_uu,
    const float* __restrict__ W1_iu, short* __restrict__ pW0_uu, short* __restrict__ pW0_ui,
    short* __restrict__ pW0_iu, short* __restrict__ pW1_uu, short* __restrict__ pW1_iu,
    int nconvU, int nconvI) {
  __shared__ int h[NBUCK];
  int b = blockIdx.x;
  int tid = threadIdx.x;
  if (b < nconvU + nconvI) {
    const float* src;
    unsigned* dst;
    int t;
    if (b < nconvU) { src = Eu; dst = Eu_b; t = b * 256 + tid; }
    else { src = Ei; dst = Ei_b; t = (b - nconvU) * 256 + tid; }
    const float4* s4 = (const float4*)src;
    float4 x = s4[(size_t)t * 2], y = s4[(size_t)t * 2 + 1];
    uint4 o;
    o.x = pack_bf16(x.x, x.y);
    o.y = pack_bf16(x.z, x.w);
    o.z = pack_bf16(y.x, y.y);
    o.w = pack_bf16(y.z, y.w);
    ((uint4*)dst)[t] = o;
    return;
  }
  b -= nconvU + nconvI;
  if (b < 3 * NSB) {
    int t = b / NSB, k = b % NSB;
    if (tid < NBUCK) h[tid] = 0;
    __syncthreads();
    const int* d = (t == 0) ? d_uu : (t == 1) ? d_iu : d_ui;
    int e0 = k * SCH, e1 = min(e0 + SCH, NEDGE);
    for (int e = e0 + tid; e < e1; e += 256) atomicAdd(&h[d[e] >> BSH], 1);
    __syncthreads();
    if (tid < NBUCK) M[t * (NBUCK * NSB) + tid * NSB + k] = h[tid];
    return;
  }
  b -= 3 * NSB;
  int t = b * 256 + tid;
  const float* src;
  short* dst;
  int base;
  bool w1 = false;
  if (t < 16384) { src = W0_uu; dst = pW0_uu; base = t; }
  else if (t < 32768) { src = W0_ui; dst = pW0_ui; base = t - 16384; }
  else if (t < 49152) { src = W0_iu; dst = pW0_iu; base = t - 32768; }
  else if (t < 51200) { src = W1_uu; dst = pW1_uu; base = t - 49152; w1 = true; }
  else if (t < 53248) { src = W1_iu; dst = pW1_iu; base = t - 51200; w1 = true; }
  else return;
  int j = base & 7;
  int lane = (base >> 3) & 63;
  int frag = base >> 9;
  int quad = lane >> 4, l16 = lane & 15;
  float val;
  if (!w1) {
    int kc = frag >> 3, nt = frag & 7;
    val = src[(kc * 32 + quad * 8 + j) * 128 + nt * 16 + l16];
  } else {
    int kc = frag;
    val = src[(kc * 32 + quad * 8 + j) * 16 + l16];
  }
  dst[base] = bf16_bits(val);
}

// ---------------- scanM: per-(bucket) local exclusive offsets across blocks + bucket totals ----
__global__ __launch_bounds__(256) void scanM_kernel(int* __restrict__ M,
                                                    int* __restrict__ Btot) {
  int t = blockIdx.x / NBUCK, b = blockIdx.x % NBUCK;
  int* Mt = M + t * (NBUCK * NSB) + b * NSB;
  __shared__ int wls[4];
  __shared__ int tot;
  int tid = threadIdx.x, lane = tid & 63, wv = tid >> 6;
  int v = Mt[tid];
  int x = v;
#pragma unroll
  for (int d = 1; d < 64; d <<= 1) {
    int y = __shfl_up(x, d, 64);
    if (lane >= d) x += y;
  }
  if (lane == 63) wls[wv] = x;
  __syncthreads();
  if (tid == 0) {
    int r = 0;
#pragma unroll
    for (int i = 0; i < 4; i++) { int tt = wls[i]; wls[i] = r; r += tt; }
    tot = r;
  }
  __syncthreads();
  Mt[tid] = x - v + wls[wv];  // local exclusive offset within bucket
  if (tid == 0) Btot[t * NBUCK + b] = tot;
}

// ---------------- scanB: exclusive scan of bucket totals -> global bucket bases ----------------
__global__ __launch_bounds__(256) void scanB_kernel(const int* __restrict__ Btot,
                                                    int* __restrict__ Bbase) {
  int t = blockIdx.x;
  __shared__ int wls[4];
  int tid = threadIdx.x, lane = tid & 63, wv = tid >> 6;
  int v = (tid < NBUCK) ? Btot[t * NBUCK + tid] : 0;
  int x = v;
#pragma unroll
  for (int d = 1; d < 64; d <<= 1) {
    int y = __shfl_up(x, d, 64);
    if (lane >= d) x += y;
  }
  if (lane == 63) wls[wv] = x;
  __syncthreads();
  if (tid == 0) {
    int r = 0;
#pragma unroll
    for (int i = 0; i < 4; i++) { int tt = wls[i]; wls[i] = r; r += tt; }
  }
  __syncthreads();
  if (tid < NBUCK) Bbase[t * NBUCK + tid] = x - v + wls[wv];
}

// ---------------- coarse scatter: block-private dense pair writes ----------------
__global__ __launch_bounds__(256) void coarse_scatter_kernel(
    const int* __restrict__ s_uu, const int* __restrict__ d_uu,
    const int* __restrict__ s_iu, const int* __restrict__ d_iu,
    const int* __restrict__ s_ui, const int* __restrict__ d_ui,
    const int* __restrict__ M, const int* __restrict__ Bbase, uint2* __restrict__ pairs) {
  __shared__ int cur[NBUCK];
  int t = blockIdx.x / NSB, k = blockIdx.x % NSB;
  int tid = threadIdx.x;
  if (tid < NBUCK) cur[tid] = M[t * (NBUCK * NSB) + tid * NSB + k] + Bbase[t * NBUCK + tid];
  __syncthreads();
  const int* src = (t == 0) ? s_uu : (t == 1) ? s_iu : s_ui;
  const int* dst = (t == 0) ? d_uu : (t == 1) ? d_iu : d_ui;
  uint2* pr = pairs + (size_t)t * NEDGE;
  int e0 = k * SCH, e1 = min(e0 + SCH, NEDGE);
  for (int e = e0 + tid; e < e1; e += 256) {
    int d = dst[e];
    int pos = atomicAdd(&cur[d >> BSH], 1);
    pr[pos] = make_uint2((unsigned)src[e], (unsigned)d);
  }
}

// ---------------- fine sort: LDS hist + LDS scan -> off[] write + ssrc scatter ----------------
__global__ __launch_bounds__(256) void fine_sort_kernel(
    const uint2* __restrict__ pairs, const int* __restrict__ Bbase,
    const int* __restrict__ Btot,
    int* __restrict__ off_uu, int* __restrict__ off_iu, int* __restrict__ off_ui,
    int* __restrict__ ssrc_uu, int* __restrict__ ssrc_iu, int* __restrict__ ssrc_ui) {
  __shared__ int h[1 << BSH];
  __shared__ int wls[4];
  int t = blockIdx.x / NBUCK, b = blockIdx.x % NBUCK;
  int tid = threadIdx.x, lane = tid & 63, wv = tid >> 6;
  int* off = (t == 0) ? off_uu : (t == 1) ? off_iu : off_ui;
  int* ss = (t == 0) ? ssrc_uu : (t == 1) ? ssrc_iu : ssrc_ui;
  const uint2* pr = pairs + (size_t)t * NEDGE;
  int base = b << BSH;
  int base_off = Bbase[t * NBUCK + b];
  int cnt = Btot[t * NBUCK + b];
  h[tid] = 0;
  h[tid + 256] = 0;
  __syncthreads();
  for (int e = base_off + tid; e < base_off + cnt; e += 256)
    atomicAdd(&h[(int)pr[e].y - base], 1);
  __syncthreads();
  int h0 = h[2 * tid], h1 = h[2 * tid + 1];
  int s = h0 + h1, x = s;
#pragma unroll
  for (int d = 1; d < 64; d <<= 1) {
    int y = __shfl_up(x, d, 64);
    if (lane >= d) x += y;
  }
  if (lane == 63) wls[wv] = x;
  __syncthreads();
  if (tid == 0) {
    int r = 0;
#pragma unroll
    for (int i = 0; i < 4; i++) { int tt = wls[i]; wls[i] = r; r += tt; }
  }
  __syncthreads();
  int excl = base_off + x - s + wls[wv];
  h[2 * tid] = excl;
  h[2 * tid + 1] = excl + h0;
  __syncthreads();
  int nn = min(1 << BSH, NU - base);
  for (int i = tid; i < nn; i += 256) off[base + i] = h[i];
  if (b == NBUCK - 1 && tid == 0) off[NU] = base_off + cnt;  // = NEDGE
  __syncthreads();
  for (int e = base_off + tid; e < base_off + cnt; e += 256) {
    uint2 p = pr[e];
    int pos = atomicAdd(&h[(int)p.y - base], 1);
    ss[pos] = (int)p.x;
  }
}

// ---------------- segment mean (3 etypes): 4 nodes/wave, masked 8-wide gather chunks ----------
__global__ __launch_bounds__(256) void agg3_kernel(
    const unsigned* __restrict__ Xu, const void* __restrict__ Xi, int xi_bf16,
    const int* __restrict__ off_ui, const int* __restrict__ off_uu, const int* __restrict__ off_iu,
    const int* __restrict__ s_ui, const int* __restrict__ s_uu, const int* __restrict__ s_iu,
    uint4* __restrict__ A_ui, uint4* __restrict__ A_uu, uint4* __restrict__ A_iu, int nb1) {
  int seg = blockIdx.x / nb1;
  int node = (blockIdx.x % nb1) * 16 + (threadIdx.x >> 4);
  int l16 = threadIdx.x & 15;
  const int* off;
  const int* ss;
  uint4* A;
  if (seg == 0) { off = off_ui; ss = s_ui; A = A_ui; }
  else if (seg == 1) { off = off_uu; ss = s_uu; A = A_uu; }
  else { off = off_iu; ss = s_iu; A = A_iu; }
  if (node >= NPAD) return;
  float ac[8];
#pragma unroll
  for (int j = 0; j < 8; j++) ac[j] = 0.f;
  int deg = 0;
  if (node < NU) {
    int s0 = off[node], s1 = off[node + 1];
    deg = s1 - s0;
    if (deg > 0) {
      if (seg < 2 || xi_bf16) {
        const uint4* X = (const uint4*)((seg < 2) ? Xu : (const unsigned*)Xi);
        for (int e = s0; e < s1; e += 8) {
          // 8 predicated concurrent gathers: clamp index, weight 0/1
          int idx[8];
          float wt[8];
#pragma unroll
          for (int j = 0; j < 8; j++) {
            int ee = e + j;
            bool v = ee < s1;
            idx[j] = ss[v ? ee : s1 - 1];
            wt[j] = v ? 1.f : 0.f;
          }
          uint4 vv[8];
#pragma unroll
          for (int j = 0; j < 8; j++) vv[j] = X[(size_t)idx[j] * 16 + l16];
#pragma unroll
          for (int j = 0; j < 8; j++) {
            bf2_accw(vv[j].x, wt[j], ac[0], ac[1]);
            bf2_accw(vv[j].y, wt[j], ac[2], ac[3]);
            bf2_accw(vv[j].z, wt[j], ac[4], ac[5]);
            bf2_accw(vv[j].w, wt[j], ac[6], ac[7]);
          }
        }
      } else {
        const float4* Xf = (const float4*)Xi;
        for (int e = s0; e < s1; e += 4) {
          int idx[4];
          float wt[4];
#pragma unroll
          for (int j = 0; j < 4; j++) {
            int ee = e + j;
            bool v = ee < s1;
            idx[j] = ss[v ? ee : s1 - 1];
            wt[j] = v ? 1.f : 0.f;
          }
#pragma unroll
          for (int j = 0; j < 4; j++) {
            float4 pa = Xf[(size_t)idx[j] * 32 + l16 * 2];
            float4 qa = Xf[(size_t)idx[j] * 32 + l16 * 2 + 1];
            ac[0] = fmaf(pa.x, wt[j], ac[0]); ac[1] = fmaf(pa.y, wt[j], ac[1]);
            ac[2] = fmaf(pa.z, wt[j], ac[2]); ac[3] = fmaf(pa.w, wt[j], ac[3]);
            ac[4] = fmaf(qa.x, wt[j], ac[4]); ac[5] = fmaf(qa.y, wt[j], ac[5]);
            ac[6] = fmaf(qa.z, wt[j], ac[6]); ac[7] = fmaf(qa.w, wt[j], ac[7]);
          }
        }
      }
    }
  }
  float inv = 1.0f / fmaxf((float)deg, 1.0f);
  uint4 o;
  o.x = pack_bf16(ac[0] * inv, ac[1] * inv);
  o.y = pack_bf16(ac[2] * inv, ac[3] * inv);
  o.z = pack_bf16(ac[4] * inv, ac[5] * inv);
  o.w = pack_bf16(ac[6] * inv, ac[7] * inv);
  A[(size_t)node * 16 + l16] = o;
}

// ---------------- fused MFMA rows ----------------
__global__ __launch_bounds__(256) void rows_mfma_kernel(
    const __hip_bfloat16* __restrict__ A_ui, const __hip_bfloat16* __restrict__ A_uu,
    const __hip_bfloat16* __restrict__ A_iu, const int* __restrict__ off_ui,
    const int* __restrict__ off_uu, const int* __restrict__ off_iu,
    const short* __restrict__ pW0_ui, const short* __restrict__ pW0_uu,
    const short* __restrict__ pW0_iu, const float* __restrict__ b0_ui,
    const float* __restrict__ b0_uu, const float* __restrict__ b0_iu,
    const short* __restrict__ pW1_iu, const short* __restrict__ pW1_uu,
    const float* __restrict__ b1_iu, const float* __restrict__ b1_uu,
    float* __restrict__ P_iu, float* __restrict__ P_uu, int nbi) {
  __shared__ float hs[4][2560];

  const int tid = threadIdx.x;
  const int w = tid >> 6, lane = tid & 63;
  const int quad = lane >> 4, l16 = lane & 15;
  const bool user = (int)blockIdx.x >= nbi;
  const int blk = user ? (int)blockIdx.x - nbi : (int)blockIdx.x;
  const int rb = blk * 64 + w * 16;

  const __hip_bfloat16* A0 = user ? A_uu : A_ui;
  const int* off0 = user ? off_uu : off_ui;
  const short* W0a = user ? pW0_uu : pW0_ui;
  const float* b0a = user ? b0_uu : b0_ui;
  const short* W1p = user ? pW1_uu : pW1_iu;
  const float* b1v = user ? b1_uu : b1_iu;
  float* P = user ? P_uu : P_iu;

  float m0[4], m1[4];
#pragma unroll
  for (int r = 0; r < 4; r++) {
    int rr = rb + quad * 4 + r;
    m0[r] = 0.f;
    m1[r] = 0.f;
    if (rr < NU) {
      m0[r] = (off0[rr + 1] > off0[rr]) ? 1.f : 0.f;
      if (user) m1[r] = (off_iu[rr + 1] > off_iu[rr]) ? 1.f : 0.f;
    }
  }

  f32x4 acc[8];
#pragma unroll
  for (int nt = 0; nt < 8; nt++) {
    float ba = b0a[nt * 16 + l16];
    float bb = user ? b0_iu[nt * 16 + l16] : 0.f;
#pragma unroll
    for (int r = 0; r < 4; r++) acc[nt][r] = ba * m0[r] + bb * m1[r];
  }

  const short8* A0v = (const short8*)(A0 + (size_t)(rb + l16) * DIN);
  const short8* A1v = (const short8*)(A_iu + (size_t)(rb + l16) * DIN);
  const short8* B0p = (const short8*)W0a;
  const short8* B1p = (const short8*)pW0_iu;

#pragma unroll
  for (int kc = 0; kc < 4; kc++) {
    short8 a0 = A0v[kc * 4 + quad];
    short8 a1 = user ? A1v[kc * 4 + quad] : a0;
#pragma unroll
    for (int nt = 0; nt < 8; nt++) {
      short8 b0 = B0p[(kc * 8 + nt) * 64 + lane];
      acc[nt] = __builtin_amdgcn_mfma_f32_16x16x32_bf16(a0, b0, acc[nt], 0, 0, 0);
      if (user) {
        short8 bb = B1p[(kc * 8 + nt) * 64 + lane];
        acc[nt] = __builtin_amdgcn_mfma_f32_16x16x32_bf16(a1, bb, acc[nt], 0, 0, 0);
      }
    }
  }

  float* hw = &hs[w][0];
#pragma unroll
  for (int nt = 0; nt < 8; nt++) {
    int col = nt * 16 + l16;
    float4 v;
    v.x = fmaxf(acc[nt][0], 0.f);
    v.y = fmaxf(acc[nt][1], 0.f);
    v.z = fmaxf(acc[nt][2], 0.f);
    v.w = fmaxf(acc[nt][3], 0.f);
    *(float4*)&hw[col * 20 + quad * 4] = v;
  }
  __syncthreads();

  f32x4 acc2;
  {
    float bv = b1v[l16];
    acc2[0] = bv; acc2[1] = bv; acc2[2] = bv; acc2[3] = bv;
  }
  const short8* W1f = (const short8*)W1p;
#pragma unroll
  for (int kc = 0; kc < 4; kc++) {
    float f[8];
#pragma unroll
    for (int j = 0; j < 8; j++) f[j] = hw[(kc * 32 + quad * 8 + j) * 20 + l16];
    union { uint4 u; short8 s; } hf;
    hf.u.x = pack_bf16(f[0], f[1]);
    hf.u.y = pack_bf16(f[2], f[3]);
    hf.u.z = pack_bf16(f[4], f[5]);
    hf.u.w = pack_bf16(f[6], f[7]);
    short8 bw = W1f[kc * 64 + lane];
    acc2 = __builtin_amdgcn_mfma_f32_16x16x32_bf16(hf.s, bw, acc2, 0, 0, 0);
  }
#pragma unroll
  for (int r = 0; r < 4; r++) {
    int rr = rb + quad * 4 + r;
    if (rr < NU) P[(size_t)rr * DOUT + l16] = acc2[r];
  }
}

// ---------------- fused output: 4 nodes/wave x 4 edge-slots x float4 ----------------
__global__ __launch_bounds__(256) void out_kernel(const float4* __restrict__ P_uu,
                                                  const float4* __restrict__ P_iu,
                                                  const int* __restrict__ off_uu,
                                                  const int* __restrict__ s_uu,
                                                  const int* __restrict__ off_iu,
                                                  const int* __restrict__ s_iu,
                                                  float4* __restrict__ out) {
  int w = threadIdx.x >> 6, lane = threadIdx.x & 63;
  int q = lane & 3;            // float4 quad within 16-float row
  int sl = (lane >> 2) & 3;    // edge slot
  int nl = lane >> 4;          // node within wave
  int node = blockIdx.x * 16 + w * 4 + nl;  // NU == 6250*16 exactly
  float4 a = make_float4(0.f, 0.f, 0.f, 0.f);
  float4 b = a;
  int s0 = off_uu[node], s1 = off_uu[node + 1];
  for (int e = s0 + sl; e < s1; e += 4) {
    float4 v = P_uu[(size_t)s_uu[e] * 4 + q];
    a.x += v.x; a.y += v.y; a.z += v.z; a.w += v.w;
  }
  int t0 = off_iu[node], t1 = off_iu[node + 1];
  for (int e = t0 + sl; e < t1; e += 4) {
    float4 v = P_iu[(size_t)s_iu[e] * 4 + q];
    b.x += v.x; b.y += v.y; b.z += v.z; b.w += v.w;
  }
  float ia = 1.0f / fmaxf((float)(s1 - s0), 1.0f);
  float ib = 1.0f / fmaxf((float)(t1 - t0), 1.0f);
  float4 r;
  r.x = a.x * ia + b.x * ib;
  r.y = a.y * ia + b.y * ib;
  r.z = a.z * ia + b.z * ib;
  r.w = a.w * ia + b.w * ib;
  // reduce across the 4 edge slots (lane bits 2-3)
  r.x += __shfl_xor(r.x, 4, 64); r.y += __shfl_xor(r.y, 4, 64);
  r.z += __shfl_xor(r.z, 4, 64); r.w += __shfl_xor(r.w, 4, 64);
  r.x += __shfl_xor(r.x, 8, 64); r.y += __shfl_xor(r.y, 8, 64);
  r.z += __shfl_xor(r.z, 8, 64); r.w += __shfl_xor(r.w, 8, 64);
  if (sl == 0) out[(size_t)node * 4 + q] = r;
}

extern "C" void kernel_launch(void* const* d_in, const int* in_sizes, int n_in,
                              void* d_out, int out_size, void* d_ws, size_t ws_size,
                              hipStream_t stream) {
  (void)in_sizes; (void)n_in; (void)out_size;
  const float* embed_user = (const float*)d_in[0];
  const float* embed_item = (const float*)d_in[1];
  const int* src_uu = (const int*)d_in[2];
  const int* dst_uu = (const int*)d_in[3];
  const int* src_ui = (const int*)d_in[4];
  const int* dst_ui = (const int*)d_in[5];
  const int* src_iu = (const int*)d_in[6];
  const int* dst_iu = (const int*)d_in[7];
  const float* W0_uu = (const float*)d_in[8];
  const float* b0_uu = (const float*)d_in[9];
  const float* W0_ui = (const float*)d_in[10];
  const float* b0_ui = (const float*)d_in[11];
  const float* W0_iu = (const float*)d_in[12];
  const float* b0_iu = (const float*)d_in[13];
  const float* W1_uu = (const float*)d_in[14];
  const float* b1_uu = (const float*)d_in[15];
  const float* W1_iu = (const float*)d_in[18];
  const float* b1_iu = (const float*)d_in[19];
  float* out = (float*)d_out;

  char* ws = (char*)d_ws;
  unsigned* Eu_b = (unsigned*)(ws + W_EU * 4);
  unsigned* A_ui = (unsigned*)(ws + W_AUI * 4);
  unsigned* A_uu = (unsigned*)(ws + W_AUU * 4);
  unsigned* A_iu = (unsigned*)(ws + W_AIU * 4);
  short* pW0_uu = (short*)(ws + W_PW * 4);
  short* pW0_ui = pW0_uu + 16384;
  short* pW0_iu = pW0_uu + 32768;
  short* pW1_uu = pW0_uu + 49152;
  short* pW1_iu = pW0_uu + 51200;
  int* off_uu = (int*)(ws + W_OFFU * 4);
  int* off_iu = (int*)(ws + W_OFFI * 4);
  int* off_ui = (int*)(ws + W_OFFX * 4);
  int* ssrc_uu = (int*)(ws + W_SUU * 4);
  int* ssrc_iu = (int*)(ws + W_SIU * 4);
  int* ssrc_ui = (int*)(ws + W_SUI * 4);
  unsigned* Ei_b = (unsigned*)(ws + W_EI * 4);
  uint2* pairs = (uint2*)A_ui;           // 3.6M w, dead before agg3 writes A_ui
  int* M = (int*)A_uu;                   // 150,528 w, dead before agg3 writes A_uu
  int* Btot = M + NBUCK * NSB * 3;       // 588 w
  int* Bbase = Btot + NBUCK * 3;         // 588 w (still within A_uu region)
  float* P_iu = (float*)Eu_b;            // Eu_b dead after agg3
  float* P_uu = P_iu + 1600000;

  const int full = (ws_size >= WS_FULL_BYTES) ? 1 : 0;
  const int nconvU = 6250, nconvI = full ? 6250 : 0;
  const void* Xi = full ? (const void*)Ei_b : (const void*)embed_item;

  prep_kernel<<<nconvU + nconvI + 3 * NSB + 208, 256, 0, stream>>>(
      embed_user, embed_item, Eu_b, Ei_b, dst_uu, dst_iu, dst_ui, M,
      W0_uu, W0_ui, W0_iu, W1_uu, W1_iu, pW0_uu, pW0_ui, pW0_iu, pW1_uu, pW1_iu,
      nconvU, nconvI);

  scanM_kernel<<<3 * NBUCK, 256, 0, stream>>>(M, Btot);
  scanB_kernel<<<3, 256, 0, stream>>>(Btot, Bbase);
  coarse_scatter_kernel<<<3 * NSB, 256, 0, stream>>>(src_uu, dst_uu, src_iu, dst_iu,
                                                     src_ui, dst_ui, M, Bbase, pairs);
  fine_sort_kernel<<<3 * NBUCK, 256, 0, stream>>>(pairs, Bbase, Btot,
                                                  off_uu, off_iu, off_ui,
                                                  ssrc_uu, ssrc_iu, ssrc_ui);

  const int nb1 = NPAD / 16;
  agg3_kernel<<<3 * nb1, 256, 0, stream>>>(Eu_b, Xi, full, off_ui, off_uu, off_iu,
                                           ssrc_ui, ssrc_uu, ssrc_iu,
                                           (uint4*)A_ui, (uint4*)A_uu, (uint4*)A_iu, nb1);

  const int nbi = NPAD / 64;
  rows_mfma_kernel<<<2 * nbi, 256, 0, stream>>>(
      (const __hip_bfloat16*)A_ui, (const __hip_bfloat16*)A_uu, (const __hip_bfloat16*)A_iu,
      off_ui, off_uu, off_iu, pW0_ui, pW0_uu, pW0_iu, b0_ui, b0_uu, b0_iu,
      pW1_iu, pW1_uu, b1_iu, b1_uu, P_iu, P_uu, nbi);

  out_kernel<<<NU / 16, 256, 0, stream>>>((const float4*)P_uu, (const float4*)P_iu,
                                          off_uu, ssrc_uu, off_iu, ssrc_iu,
                                          (float4*)out);
}